// Round 16
// baseline (426.506 us; speedup 1.0000x reference)
//
#include <hip/hip_runtime.h>
#include <hip/hip_bf16.h>

#define B_ 4
#define N_ 2048
#define D_ 300
#define Y_ 20000
#define ROWS (B_*N_)   // 8192

typedef __attribute__((ext_vector_type(8))) short bf16x8;
typedef __attribute__((ext_vector_type(4))) float f32x4;

__device__ __forceinline__ unsigned short f2bf(float f) {  // RNE f32->bf16
  unsigned u = __float_as_uint(f);
  unsigned r = (u + 0x7FFFu + ((u >> 16) & 1u)) >> 16;
  return (unsigned short)r;
}

__device__ __forceinline__ void gl_lds16(const unsigned short* g, unsigned short* l) {
  __builtin_amdgcn_global_load_lds(
      (const __attribute__((address_space(1))) void*)g,
      (__attribute__((address_space(3))) void*)l, 16, 0, 0);
}

// ---- X = E_v[M_s] (f32) + fused Xp fragment pack ----
__global__ __launch_bounds__(256) void k_gather_pack(const int* __restrict__ M_s,
    const float* __restrict__ E_v, float* __restrict__ X,
    unsigned short* __restrict__ Xp) {
  __shared__ float xs[320];
  int row = blockIdx.x, tid = threadIdx.x;
  int tok = M_s[row];
  const float* src = E_v + (size_t)tok * D_;
  for (int d = tid; d < 320; d += 256) xs[d] = (d < D_) ? src[d] : 0.f;
  __syncthreads();
  float* dst = X + (size_t)row * D_;
  for (int d = tid; d < D_; d += 256) dst[d] = xs[d];
  if (tid < 40) {
    int kt = tid >> 2, j = tid & 3;
    int tile = row >> 7, fb = (row >> 4) & 7, rl = row & 15;
    unsigned short v[8];
    #pragma unroll
    for (int e = 0; e < 8; ++e) v[e] = f2bf(xs[kt*32 + j*8 + e]);
    size_t off_ = ((size_t)(tile*10 + kt))*4096 + fb*512 + rl*8 + j*128;
    ushort4* o = (ushort4*)&Xp[off_];
    o[0] = make_ushort4(v[0],v[1],v[2],v[3]);
    o[1] = make_ushort4(v[4],v[5],v[6],v[7]);
  }
}

// ---- pack f32 [nrows,ncols] row-major -> bf16 MFMA fragment chunks ----
__global__ __launch_bounds__(256) void k_pack(const float* __restrict__ src,
    unsigned short* __restrict__ dst, int nrows, int ncols, int KT) {
  int chunk = blockIdx.x;
  int tile = chunk / KT, kt = chunk - tile*KT;
  size_t obase = (size_t)chunk * 4096;
  #pragma unroll
  for (int p = 0; p < 2; ++p) {
    int idx = p*256 + threadIdx.x;
    int fb = idx >> 6, l = idx & 63;
    int row = tile*128 + fb*16 + (l & 15);
    int gk = kt*32 + (l >> 4)*8;
    unsigned short v[8];
    #pragma unroll
    for (int e = 0; e < 8; ++e) {
      int k = gk + e;
      float f = (row < nrows && k < ncols) ? src[(size_t)row*ncols + k] : 0.f;
      v[e] = f2bf(f);
    }
    ushort4* o = (ushort4*)&dst[obase + (size_t)idx*8];
    o[0] = make_ushort4(v[0],v[1],v[2],v[3]);
    o[1] = make_ushort4(v[4],v[5],v[6],v[7]);
  }
}

// ---- transposing pack via LDS (coalesced source reads) ----
__global__ __launch_bounds__(256) void k_packT(const float* __restrict__ src,
    unsigned short* __restrict__ dst, int src_rows, int src_cols, int KT,
    size_t src_bstride, size_t dst_bchunks) {
  __shared__ float ls[32*133];
  int chunk = blockIdx.x, b = blockIdx.y, tid = threadIdx.x;
  const float* s = src + (size_t)b * src_bstride;
  unsigned short* d = dst + ((size_t)b * dst_bchunks + chunk) * 4096;
  int tile = chunk / KT, kt = chunk - tile*KT;
  int c0 = tile*128, k0 = kt*32;
  for (int i = tid; i < 4096; i += 256) {
    int r = i >> 7, c = i & 127;
    int sr = k0 + r, sc = c0 + c;
    ls[r*133 + c] = (sr < src_rows && sc < src_cols) ? s[(size_t)sr*src_cols + sc] : 0.f;
  }
  __syncthreads();
  #pragma unroll
  for (int p = 0; p < 2; ++p) {
    int idx = p*256 + tid;
    int fb = idx >> 6, l = idx & 63;
    int r = fb*16 + (l & 15);
    int kl = (l >> 4)*8;
    unsigned short v[8];
    #pragma unroll
    for (int e = 0; e < 8; ++e) v[e] = f2bf(ls[(kl + e)*133 + r]);
    ushort4* o = (ushort4*)&d[(size_t)idx*8];
    o[0] = make_ushort4(v[0],v[1],v[2],v[3]);
    o[1] = make_ushort4(v[4],v[5],v[6],v[7]);
  }
}

// ========== 256x128-tile KT=10 GEMM: 8 waves, stage-all-B, barrier-free =====
// Direct NT stores from acc (no LDS epilogue): L2 merges the 64B fragments
// (round-10 equivalence); kills 8 epilogue barriers + 1-of-4-wave serialization.
// EPI 0: plain; 1: score (-dist, pad mask).  NT: nontemporal.  SWZ: XCD swizzle.
template<int EPI, bool NT, bool SWZ>
__global__ __launch_bounds__(512, 4) void k_gemm256(
    const unsigned short* __restrict__ Ap, const unsigned short* __restrict__ Bp,
    float* __restrict__ out, const int* __restrict__ Ms,
    int MTB, int NTB, int ncols)
{
  __shared__ __align__(16) unsigned short bstage[10][4096];   // 80 KB
  int nt, mt, z;
  if (SWZ) {
    int wg = blockIdx.x;
    int cpx = (MTB*NTB) >> 3;           // caller guarantees grid%8==0
    int swz = (wg & 7)*cpx + (wg >> 3);
    mt = swz % MTB; nt = swz / MTB; z = 0;
  } else { nt = blockIdx.x; mt = blockIdx.y; z = blockIdx.z; }
  const int tid = threadIdx.x;
  const int wave = tid >> 6, lane = tid & 63;
  const int wm = wave >> 1, wn = wave & 1;          // wm 0..3, wn 0..1
  const int mtile2 = (z*MTB + mt)*2 + (wm >> 1);    // which 128-row A tile
  const unsigned short* Ab = Ap + (size_t)mtile2 * 10 * 4096;
  const unsigned short* Bb = Bp + (size_t)(z*NTB + nt) * 10 * 4096;

  #pragma unroll
  for (int kt = 0; kt < 10; ++kt)
    gl_lds16(Bb + kt*4096 + wave*512 + lane*8, &bstage[kt][wave*512]);

  const unsigned short* ga = Ab + ((wm & 1)*4)*512 + lane*8;
  __syncthreads();   // vmcnt(0) drain == all B staged

  f32x4 acc[4][4] = {};
  #pragma unroll
  for (int kt = 0; kt < 10; ++kt) {
    bf16x8 a4[4], b4[4];
    #pragma unroll
    for (int i = 0; i < 4; ++i)
      a4[i] = *(const bf16x8*)(ga + kt*4096 + i*512);
    #pragma unroll
    for (int i = 0; i < 4; ++i)
      b4[i] = *(const bf16x8*)&bstage[kt][(wn*4 + i)*512 + lane*8];
    #pragma unroll
    for (int mi = 0; mi < 4; ++mi)
      #pragma unroll
      for (int ni = 0; ni < 4; ++ni)
        acc[mi][ni] = __builtin_amdgcn_mfma_f32_16x16x32_bf16(
            a4[mi], b4[ni], acc[mi][ni], 0, 0, 0);
  }

  // ---- direct epilogue from acc: C/D col=lane&15, row=(lane>>4)*4+r ----
  const int lr0 = (lane >> 4) << 2;
  const int lc0 = wn*64 + (lane & 15);
  const size_t grow0 = ((size_t)(z*MTB + mt))*256 + wm*64 + lr0;
  const int rb0 = mt*256 + wm*64 + lr0;             // row within batch (EPI=1)
  int tok[4];
  if (EPI == 1) {
    #pragma unroll
    for (int ni = 0; ni < 4; ++ni)
      tok[ni] = Ms[z*N_ + (nt<<7) + lc0 + ni*16];
  }
  #pragma unroll
  for (int ni = 0; ni < 4; ++ni) {
    int gc = (nt << 7) + lc0 + ni*16;
    if (gc >= ncols) continue;
    #pragma unroll
    for (int mi = 0; mi < 4; ++mi) {
      #pragma unroll
      for (int r = 0; r < 4; ++r) {
        float v = acc[mi][ni][r];
        if (EPI == 1) {
          int rb = rb0 + mi*16 + r;
          int dd = rb - gc; if (dd < 0) dd = -dd; if (dd > 10) dd = 10;
          v -= (float)dd;
          if (tok[ni] == 0) v = -3.0e38f;
        }
        size_t go = (grow0 + mi*16 + r) * (size_t)ncols + gc;
        if (NT) __builtin_nontemporal_store(v, &out[go]);
        else    out[go] = v;
      }
    }
  }
}

// ================= KT=10 GEMM (128x128): stage-all-B, barrier-free ==========
template<int EPI, bool NT, bool PACKOUT, bool SWZ>
__global__ __launch_bounds__(256) void k_gemm10(
    const unsigned short* __restrict__ Ap, const unsigned short* __restrict__ Bp,
    float* __restrict__ out, unsigned short* __restrict__ outp,
    const float* __restrict__ resid, const int* __restrict__ Ms,
    int KTd, int MTB, int NTB, int ncols)
{
  __shared__ __align__(16) union {
    unsigned short bstage[10][4096];
    float epi[64*132];
  } sm;
  int nt, mt, z;
  if (SWZ) {
    int nwg = MTB * NTB;
    int wg = blockIdx.x;
    int cpx = nwg >> 3;
    int swz = (wg & 7) * cpx + (wg >> 3);
    mt = swz % MTB; nt = swz / MTB; z = 0;
  } else {
    nt = blockIdx.x; mt = blockIdx.y; z = blockIdx.z;
  }
  const int tid = threadIdx.x;
  const int wave = tid >> 6, lane = tid & 63;
  const int wm = wave >> 1, wn = wave & 1;
  const unsigned short* Ab = Ap + (size_t)(z*MTB + mt) * 10 * 4096;
  const unsigned short* Bb = Bp + (size_t)(z*NTB + nt) * 10 * 4096;

  #pragma unroll
  for (int kt = 0; kt < 10; ++kt) {
    const unsigned short* gb = Bb + kt*4096 + wave*1024 + lane*8;
    unsigned short* lb = &sm.bstage[kt][wave*1024];
    gl_lds16(gb,       lb);
    gl_lds16(gb + 512, lb + 512);
  }

  const unsigned short* ga = Ab + (wm*4)*512 + lane*8;
  bf16x8 aA[4], aB[4];
  #pragma unroll
  for (int i = 0; i < 4; ++i) aA[i] = *(const bf16x8*)(ga + 0*4096 + i*512);
  #pragma unroll
  for (int i = 0; i < 4; ++i) aB[i] = *(const bf16x8*)(ga + 1*4096 + i*512);

  __syncthreads();

  f32x4 acc[4][4] = {};
  auto mfma_step = [&](int kt, const bf16x8* a) {
    bf16x8 bfr[4];
    #pragma unroll
    for (int i = 0; i < 4; ++i)
      bfr[i] = *(const bf16x8*)&sm.bstage[kt][(wn*4 + i)*512 + lane*8];
    #pragma unroll
    for (int mi = 0; mi < 4; ++mi)
      #pragma unroll
      for (int ni = 0; ni < 4; ++ni)
        acc[mi][ni] = __builtin_amdgcn_mfma_f32_16x16x32_bf16(
            a[mi], bfr[ni], acc[mi][ni], 0, 0, 0);
  };
  auto loadA = [&](int kt, bf16x8* d) {
    #pragma unroll
    for (int i = 0; i < 4; ++i) d[i] = *(const bf16x8*)(ga + kt*4096 + i*512);
  };

  #pragma unroll
  for (int kt = 0; kt < 10; kt += 2) {
    mfma_step(kt, aA);
    if (kt + 2 < 10) loadA(kt + 2, aA);
    mfma_step(kt + 1, aB);
    if (kt + 3 < 10) loadA(kt + 3, aB);
  }

  __syncthreads();

  const int lr0 = (lane >> 4) << 2;
  const int lc0 = wn*64 + (lane & 15);
  const size_t growbase = ((size_t)(z*MTB + mt)) << 7;
  #pragma unroll
  for (int h = 0; h < 2; ++h) {
    if (wm == h) {
      int tok[4];
      if (EPI == 1) {
        #pragma unroll
        for (int ni = 0; ni < 4; ++ni)
          tok[ni] = Ms[z*N_ + (nt<<7) + lc0 + ni*16];
      }
      #pragma unroll
      for (int mi = 0; mi < 4; ++mi) {
        #pragma unroll
        for (int ni = 0; ni < 4; ++ni) {
          int col = lc0 + ni*16;
          #pragma unroll
          for (int r = 0; r < 4; ++r) {
            int row = lr0 + mi*16 + r;
            float v = acc[mi][ni][r];
            if (EPI == 1) {
              int rb = (mt<<7) + h*64 + row;
              int gc = (nt<<7) + col;
              int dd = rb - gc; if (dd < 0) dd = -dd; if (dd > 10) dd = 10;
              v -= (float)dd;
              if (tok[ni] == 0) v = -3.0e38f;
            }
            sm.epi[row*132 + col] = v;
          }
        }
      }
    }
    __syncthreads();
    if (PACKOUT) {
      int prow = tid >> 2, pktq = tid & 3;
      int ktd = nt*4 + pktq;
      if (ktd < KTd) {
        int grl = h*64 + prow;
        int fb = grl >> 4, rl = grl & 15;
        size_t cbase = ((size_t)((z*MTB + mt)*KTd + ktd))*4096 + fb*512 + rl*8;
        #pragma unroll
        for (int oct = 0; oct < 4; ++oct) {
          unsigned short v[8];
          #pragma unroll
          for (int e = 0; e < 8; ++e)
            v[e] = f2bf(sm.epi[prow*132 + pktq*32 + oct*8 + e]);
          ushort4* o = (ushort4*)&outp[cbase + oct*128];
          o[0] = make_ushort4(v[0],v[1],v[2],v[3]);
          o[1] = make_ushort4(v[4],v[5],v[6],v[7]);
        }
      }
    } else {
      const int r0 = tid >> 5;
      const int c4 = (tid & 31) << 2;
      const int gc = (nt << 7) + c4;
      #pragma unroll
      for (int rr = r0; rr < 64; rr += 8) {
        size_t grow = growbase + h*64 + rr;
        if (gc + 3 < ncols) {
          f32x4 v = *(const f32x4*)&sm.epi[rr*132 + c4];
          if (EPI == 2) v += *(const f32x4*)&resid[grow*(size_t)ncols + gc];
          if (NT) __builtin_nontemporal_store(v, (f32x4*)&out[grow*(size_t)ncols + gc]);
          else    *(f32x4*)&out[grow*(size_t)ncols + gc] = v;
        } else {
          #pragma unroll
          for (int e = 0; e < 4; ++e) {
            int c = gc + e;
            if (c < ncols) {
              float v = sm.epi[rr*132 + c4 + e];
              if (EPI == 2) v += resid[grow*(size_t)ncols + c];
              if (NT) __builtin_nontemporal_store(v, &out[grow*(size_t)ncols + c]);
              else    out[grow*(size_t)ncols + c] = v;
            }
          }
        }
      }
    }
    __syncthreads();
  }
}

// ===== KT=64 GEMM (C = A@X): double-buffered + PACKOUT ====
__global__ __launch_bounds__(256) void k_gemm64(
    const unsigned short* __restrict__ Ap, const unsigned short* __restrict__ Bp,
    unsigned short* __restrict__ outp, int KT, int KTd, int MTB, int NTB)
{
  __shared__ __align__(16) union {
    unsigned short stage[2][2][4096];
    float epi[64*132];
  } sm;
  const int nt = blockIdx.x, mt = blockIdx.y, z = blockIdx.z;
  const int tid = threadIdx.x;
  const int wave = tid >> 6, lane = tid & 63;
  const int wm = wave >> 1, wn = wave & 1;
  const unsigned short* Ab = Ap + (size_t)(z*MTB + mt) * KT * 4096;
  const unsigned short* Bb = Bp + (size_t)(z*NTB + nt) * KT * 4096;
  f32x4 acc[4][4] = {};

  auto stage = [&](int s, int kt) {
    const unsigned short* ga = Ab + kt*4096 + wave*1024 + lane*8;
    const unsigned short* gb = Bb + kt*4096 + wave*1024 + lane*8;
    unsigned short* la = &sm.stage[s][0][wave*1024];
    unsigned short* lb = &sm.stage[s][1][wave*1024];
    gl_lds16(ga,       la);
    gl_lds16(ga + 512, la + 512);
    gl_lds16(gb,       lb);
    gl_lds16(gb + 512, lb + 512);
  };

  stage(0, 0);
  __syncthreads();
  for (int kt = 0; kt < KT; ++kt) {
    int cur = kt & 1;
    if (kt + 1 < KT) stage(cur ^ 1, kt + 1);
    bf16x8 af[4], bfr[4];
    #pragma unroll
    for (int i = 0; i < 4; ++i)
      af[i] = *(const bf16x8*)&sm.stage[cur][0][(wm*4 + i)*512 + lane*8];
    #pragma unroll
    for (int i = 0; i < 4; ++i)
      bfr[i] = *(const bf16x8*)&sm.stage[cur][1][(wn*4 + i)*512 + lane*8];
    #pragma unroll
    for (int mi = 0; mi < 4; ++mi)
      #pragma unroll
      for (int ni = 0; ni < 4; ++ni)
        acc[mi][ni] = __builtin_amdgcn_mfma_f32_16x16x32_bf16(
            af[mi], bfr[ni], acc[mi][ni], 0, 0, 0);
    __syncthreads();
  }

  const int lr0 = (lane >> 4) << 2;
  const int lc0 = wn*64 + (lane & 15);
  #pragma unroll
  for (int h = 0; h < 2; ++h) {
    if (wm == h) {
      #pragma unroll
      for (int mi = 0; mi < 4; ++mi)
        #pragma unroll
        for (int ni = 0; ni < 4; ++ni) {
          int col = lc0 + ni*16;
          #pragma unroll
          for (int r = 0; r < 4; ++r)
            sm.epi[(lr0 + mi*16 + r)*132 + col] = acc[mi][ni][r];
        }
    }
    __syncthreads();
    {
      int prow = tid >> 2, pktq = tid & 3;
      int ktd = nt*4 + pktq;
      if (ktd < KTd) {
        int grl = h*64 + prow;
        int fb = grl >> 4, rl = grl & 15;
        size_t cbase = ((size_t)((z*MTB + mt)*KTd + ktd))*4096 + fb*512 + rl*8;
        #pragma unroll
        for (int oct = 0; oct < 4; ++oct) {
          unsigned short v[8];
          #pragma unroll
          for (int e = 0; e < 8; ++e)
            v[e] = f2bf(sm.epi[prow*132 + pktq*32 + oct*8 + e]);
          ushort4* o = (ushort4*)&outp[cbase + oct*128];
          o[0] = make_ushort4(v[0],v[1],v[2],v[3]);
          o[1] = make_ushort4(v[4],v[5],v[6],v[7]);
        }
      }
    }
    __syncthreads();
  }
}

// ---- row softmax: reg-held row, 2 barriers, f32x4 NT out + packed A frags ----
__global__ __launch_bounds__(256) void k_softmax(float* __restrict__ S,
    unsigned short* __restrict__ Apk) {
  __shared__ float w[N_];        // e-values (for the pack)
  __shared__ float redm[4], reds[4];
  int row = blockIdx.x, tid = threadIdx.x;
  float* sr = S + (size_t)row * N_;
  f32x4 v0 = ((const f32x4*)sr)[tid];
  f32x4 v1 = ((const f32x4*)sr)[tid + 256];
  float vmax = fmaxf(fmaxf(fmaxf(v0.x, v0.y), fmaxf(v0.z, v0.w)),
                     fmaxf(fmaxf(v1.x, v1.y), fmaxf(v1.z, v1.w)));
  #pragma unroll
  for (int off = 32; off; off >>= 1) vmax = fmaxf(vmax, __shfl_down(vmax, off, 64));
  if ((tid & 63) == 0) redm[tid >> 6] = vmax;
  __syncthreads();
  vmax = fmaxf(fmaxf(redm[0], redm[1]), fmaxf(redm[2], redm[3]));
  f32x4 e0, e1;
  e0.x = __expf(v0.x - vmax); e0.y = __expf(v0.y - vmax);
  e0.z = __expf(v0.z - vmax); e0.w = __expf(v0.w - vmax);
  e1.x = __expf(v1.x - vmax); e1.y = __expf(v1.y - vmax);
  e1.z = __expf(v1.z - vmax); e1.w = __expf(v1.w - vmax);
  ((f32x4*)w)[tid] = e0;
  ((f32x4*)w)[tid + 256] = e1;
  float vsum = (e0.x + e0.y + e0.z + e0.w) + (e1.x + e1.y + e1.z + e1.w);
  #pragma unroll
  for (int off = 32; off; off >>= 1) vsum += __shfl_down(vsum, off, 64);
  if ((tid & 63) == 0) reds[tid >> 6] = vsum;
  __syncthreads();               // orders reds AND w(e) writes
  float inv = 1.f / ((reds[0] + reds[1]) + (reds[2] + reds[3]));
  f32x4 o0 = e0 * inv, o1 = e1 * inv;
  __builtin_nontemporal_store(o0, &((f32x4*)sr)[tid]);
  __builtin_nontemporal_store(o1, &((f32x4*)sr)[tid + 256]);
  int kt = tid >> 2, j = tid & 3;
  int m0 = kt*32 + j*8;
  int fb = (row >> 4) & 7, rl = row & 15;
  unsigned short v[8];
  #pragma unroll
  for (int e = 0; e < 8; ++e) v[e] = f2bf(w[m0 + e] * inv);
  size_t off_ = ((size_t)((row >> 7)*64 + kt))*4096 + fb*512 + rl*8 + j*128;
  ushort4* o = (ushort4*)&Apk[off_];
  o[0] = make_ushort4(v[0],v[1],v[2],v[3]);
  o[1] = make_ushort4(v[4],v[5],v[6],v[7]);
}

// ---- LayerNorm on H + fused Hp fragment pack ----
__global__ __launch_bounds__(320) void k_ln_pack(const float* __restrict__ H,
    const float* __restrict__ gamma, const float* __restrict__ beta,
    unsigned short* __restrict__ Hp) {
  __shared__ float red[5];
  __shared__ float hs[320];
  int row = blockIdx.x, tid = threadIdx.x;
  float h = (tid < D_) ? H[(size_t)row*D_ + tid] : 0.f;
  float s = h;
  #pragma unroll
  for (int off = 32; off; off >>= 1) s += __shfl_down(s, off, 64);
  if ((tid & 63) == 0) red[tid >> 6] = s;
  __syncthreads();
  float mu = (red[0]+red[1]+red[2]+red[3]+red[4]) * (1.f/(float)D_);
  float dv = (tid < D_) ? (h - mu) : 0.f;
  float s2 = dv * dv;
  #pragma unroll
  for (int off = 32; off; off >>= 1) s2 += __shfl_down(s2, off, 64);
  __syncthreads();
  if ((tid & 63) == 0) red[tid >> 6] = s2;
  __syncthreads();
  float var = (red[0]+red[1]+red[2]+red[3]+red[4]) * (1.f/(float)D_);
  float rstd = rsqrtf(var + 1e-5f);
  hs[tid] = (tid < D_) ? (dv * rstd * gamma[tid] + beta[tid]) : 0.f;
  __syncthreads();
  if (tid < 40) {
    int kt = tid >> 2, j = tid & 3;
    int tile = row >> 7, fb = (row >> 4) & 7, rl = row & 15;
    unsigned short v[8];
    #pragma unroll
    for (int e = 0; e < 8; ++e) v[e] = f2bf(hs[kt*32 + j*8 + e]);
    size_t off_ = ((size_t)(tile*10 + kt))*4096 + fb*512 + rl*8 + j*128;
    ushort4* o = (ushort4*)&Hp[off_];
    o[0] = make_ushort4(v[0],v[1],v[2],v[3]);
    o[1] = make_ushort4(v[4],v[5],v[6],v[7]);
  }
}

extern "C" void kernel_launch(void* const* d_in, const int* in_sizes, int n_in,
                              void* d_out, int out_size, void* d_ws, size_t ws_size,
                              hipStream_t stream) {
  const int*   M_s   = (const int*)d_in[0];
  const float* E_v   = (const float*)d_in[1];
  const float* E_y   = (const float*)d_in[2];
  const float* W_A   = (const float*)d_in[3];
  const float* W_O   = (const float*)d_in[4];
  const float* gamma = (const float*)d_in[5];
  const float* beta  = (const float*)d_in[6];

  float* Yl = (float*)d_out;                       // [8192, 20000]
  float* A  = Yl + (size_t)ROWS * Y_;              // [8192, 2048] (scores -> softmax in place)

  float* X  = (float*)d_ws;                        // [8192,300]
  float* QW = X  + (size_t)ROWS * D_;              // region free (packed path)
  float* H  = QW + (size_t)ROWS * D_;              // [8192,300]
  unsigned short* Ep = (unsigned short*)(H + (size_t)ROWS * D_); // packed E_y (d_ws)
  // Hpk overlays X in d_ws (X dead after residual GEMM); must NOT live in the
  // Yl region the logits GEMM writes (round-8 NaN lesson).
  unsigned short* Hpk = (unsigned short*)X;

  // packed temporaries in the dead tail of the Yl region — all consumed before
  // the final logits GEMM launches (stream-ordered).
  unsigned short* scr = (unsigned short*)(Yl + 100000000ull);
  unsigned short* Xp  = scr;                       // 2,621,440 ush
  unsigned short* QWp = Xp  + 2621440;             // 2,621,440
  unsigned short* Wap = QWp + 2621440;             //   122,880
  unsigned short* Wop = Wap + 122880;              //   122,880
  unsigned short* XTp = Wop + 122880;              // 3,145,728
  unsigned short* Cp  = XTp + 3145728;             // 2,621,440
  unsigned short* Apk = Cp  + 2621440;             // 16,777,216

  k_gather_pack<<<ROWS, 256, 0, stream>>>(M_s, E_v, X, Xp);
  k_packT <<<dim3(3*10,1), 256, 0, stream>>>(W_A, Wap, D_, D_, 10, 0, 0);
  // QW = X @ W_A -> packed QWp (epilogue fusion)
  k_gemm10<0,false,true,false><<<dim3(3,64,1), 256, 0, stream>>>(
      Xp, Wap, nullptr, QWp, nullptr, nullptr, 10, 64, 3, D_);
  // S = QW @ X^T - dist, masked  (256x128 tile, 8 waves, direct stores)
  k_gemm256<1,false,false><<<dim3(16,8,4), 512, 0, stream>>>(
      QWp, Xp, A, M_s, 8, 16, N_);
  k_softmax<<<ROWS, 256, 0, stream>>>(A, Apk);
  k_packT <<<dim3(3*64,4), 256, 0, stream>>>(X, XTp, N_, D_, 64, (size_t)N_*D_, 192);
  // C = A @ X -> packed Cp (KT=64 dbuf)
  k_gemm64<<<dim3(3,16,4), 256, 0, stream>>>(Apk, XTp, Cp, 64, 10, 16, 3);
  k_packT <<<dim3(3*10,1), 256, 0, stream>>>(W_O, Wop, D_, D_, 10, 0, 0);
  // H = C @ W_O + X
  k_gemm10<2,false,false,false><<<dim3(3,64,1), 256, 0, stream>>>(
      Cp, Wop, H, nullptr, X, nullptr, 0, 64, 3, D_);
  k_ln_pack<<<ROWS, 320, 0, stream>>>(H, gamma, beta, Hpk);
  k_pack  <<<157*10, 256, 0, stream>>>(E_y, Ep, Y_, D_, 10);
  // Yl = Hn @ E_y^T  (256x128 tile, 8 waves, XCD swizzle, direct NT stores)
  k_gemm256<0,true,true><<<dim3(157*32,1,1), 512, 0, stream>>>(
      Hpk, Ep, Yl, nullptr, 32, 157, Y_);
}

// Round 17
// 373.792 us; speedup vs baseline: 1.1410x; 1.1410x over previous
//
#include <hip/hip_runtime.h>
#include <hip/hip_bf16.h>

#define B_ 4
#define N_ 2048
#define D_ 300
#define Y_ 20000
#define ROWS (B_*N_)   // 8192

typedef __attribute__((ext_vector_type(8))) short bf16x8;
typedef __attribute__((ext_vector_type(4))) float f32x4;

__device__ __forceinline__ unsigned short f2bf(float f) {  // RNE f32->bf16
  unsigned u = __float_as_uint(f);
  unsigned r = (u + 0x7FFFu + ((u >> 16) & 1u)) >> 16;
  return (unsigned short)r;
}

__device__ __forceinline__ void gl_lds16(const unsigned short* g, unsigned short* l) {
  __builtin_amdgcn_global_load_lds(
      (const __attribute__((address_space(1))) void*)g,
      (__attribute__((address_space(3))) void*)l, 16, 0, 0);
}

// ---- X = E_v[M_s] (f32) + fused Xp fragment pack ----
__global__ __launch_bounds__(256) void k_gather_pack(const int* __restrict__ M_s,
    const float* __restrict__ E_v, float* __restrict__ X,
    unsigned short* __restrict__ Xp) {
  __shared__ float xs[320];
  int row = blockIdx.x, tid = threadIdx.x;
  int tok = M_s[row];
  const float* src = E_v + (size_t)tok * D_;
  for (int d = tid; d < 320; d += 256) xs[d] = (d < D_) ? src[d] : 0.f;
  __syncthreads();
  float* dst = X + (size_t)row * D_;
  for (int d = tid; d < D_; d += 256) dst[d] = xs[d];
  if (tid < 40) {
    int kt = tid >> 2, j = tid & 3;
    int tile = row >> 7, fb = (row >> 4) & 7, rl = row & 15;
    unsigned short v[8];
    #pragma unroll
    for (int e = 0; e < 8; ++e) v[e] = f2bf(xs[kt*32 + j*8 + e]);
    size_t off_ = ((size_t)(tile*10 + kt))*4096 + fb*512 + rl*8 + j*128;
    ushort4* o = (ushort4*)&Xp[off_];
    o[0] = make_ushort4(v[0],v[1],v[2],v[3]);
    o[1] = make_ushort4(v[4],v[5],v[6],v[7]);
  }
}

// ---- pack f32 [nrows,ncols] row-major -> bf16 MFMA fragment chunks ----
__global__ __launch_bounds__(256) void k_pack(const float* __restrict__ src,
    unsigned short* __restrict__ dst, int nrows, int ncols, int KT) {
  int chunk = blockIdx.x;
  int tile = chunk / KT, kt = chunk - tile*KT;
  size_t obase = (size_t)chunk * 4096;
  #pragma unroll
  for (int p = 0; p < 2; ++p) {
    int idx = p*256 + threadIdx.x;
    int fb = idx >> 6, l = idx & 63;
    int row = tile*128 + fb*16 + (l & 15);
    int gk = kt*32 + (l >> 4)*8;
    unsigned short v[8];
    #pragma unroll
    for (int e = 0; e < 8; ++e) {
      int k = gk + e;
      float f = (row < nrows && k < ncols) ? src[(size_t)row*ncols + k] : 0.f;
      v[e] = f2bf(f);
    }
    ushort4* o = (ushort4*)&dst[obase + (size_t)idx*8];
    o[0] = make_ushort4(v[0],v[1],v[2],v[3]);
    o[1] = make_ushort4(v[4],v[5],v[6],v[7]);
  }
}

// ---- transposing pack via LDS (coalesced source reads) ----
__global__ __launch_bounds__(256) void k_packT(const float* __restrict__ src,
    unsigned short* __restrict__ dst, int src_rows, int src_cols, int KT,
    size_t src_bstride, size_t dst_bchunks) {
  __shared__ float ls[32*133];
  int chunk = blockIdx.x, b = blockIdx.y, tid = threadIdx.x;
  const float* s = src + (size_t)b * src_bstride;
  unsigned short* d = dst + ((size_t)b * dst_bchunks + chunk) * 4096;
  int tile = chunk / KT, kt = chunk - tile*KT;
  int c0 = tile*128, k0 = kt*32;
  for (int i = tid; i < 4096; i += 256) {
    int r = i >> 7, c = i & 127;
    int sr = k0 + r, sc = c0 + c;
    ls[r*133 + c] = (sr < src_rows && sc < src_cols) ? s[(size_t)sr*src_cols + sc] : 0.f;
  }
  __syncthreads();
  #pragma unroll
  for (int p = 0; p < 2; ++p) {
    int idx = p*256 + tid;
    int fb = idx >> 6, l = idx & 63;
    int r = fb*16 + (l & 15);
    int kl = (l >> 4)*8;
    unsigned short v[8];
    #pragma unroll
    for (int e = 0; e < 8; ++e) v[e] = f2bf(ls[(kl + e)*133 + r]);
    ushort4* o = (ushort4*)&d[(size_t)idx*8];
    o[0] = make_ushort4(v[0],v[1],v[2],v[3]);
    o[1] = make_ushort4(v[4],v[5],v[6],v[7]);
  }
}

// ========== 256x128-tile KT=10 GEMM: 8 waves, stage-all-B, barrier-free =====
// R14-verified structure: LDS-staged epilogue (coalesced f32x4 stores).
// NT stores MUST go through the LDS transpose — scalar NT fragments bypass L2
// write-combining and regress 51us (round-16 lesson).
// EPI 0: plain; 1: score (-dist, pad mask).  NT: nontemporal.  SWZ: XCD swizzle.
template<int EPI, bool NT, bool SWZ>
__global__ __launch_bounds__(512, 4) void k_gemm256(
    const unsigned short* __restrict__ Ap, const unsigned short* __restrict__ Bp,
    float* __restrict__ out, const int* __restrict__ Ms,
    int MTB, int NTB, int ncols)
{
  __shared__ __align__(16) union {
    unsigned short bstage[10][4096];    // 80 KB (read-only after barrier)
    float epi[64*132];                  // epilogue quarter tile
  } sm;
  int nt, mt, z;
  if (SWZ) {
    int wg = blockIdx.x;
    int cpx = (MTB*NTB) >> 3;           // caller guarantees grid%8==0
    int swz = (wg & 7)*cpx + (wg >> 3);
    mt = swz % MTB; nt = swz / MTB; z = 0;
  } else { nt = blockIdx.x; mt = blockIdx.y; z = blockIdx.z; }
  const int tid = threadIdx.x;
  const int wave = tid >> 6, lane = tid & 63;
  const int wm = wave >> 1, wn = wave & 1;          // wm 0..3, wn 0..1
  const int mtile2 = (z*MTB + mt)*2 + (wm >> 1);    // which 128-row A tile
  const unsigned short* Ab = Ap + (size_t)mtile2 * 10 * 4096;
  const unsigned short* Bb = Bp + (size_t)(z*NTB + nt) * 10 * 4096;

  // stage all 10 B chunks: wave w covers 512B segment of each 8KB chunk
  #pragma unroll
  for (int kt = 0; kt < 10; ++kt)
    gl_lds16(Bb + kt*4096 + wave*512 + lane*8, &sm.bstage[kt][wave*512]);

  const unsigned short* ga = Ab + ((wm & 1)*4)*512 + lane*8;
  __syncthreads();   // vmcnt(0) drain == all B staged

  f32x4 acc[4][4] = {};
  #pragma unroll
  for (int kt = 0; kt < 10; ++kt) {
    bf16x8 a4[4], b4[4];
    #pragma unroll
    for (int i = 0; i < 4; ++i)
      a4[i] = *(const bf16x8*)(ga + kt*4096 + i*512);
    #pragma unroll
    for (int i = 0; i < 4; ++i)
      b4[i] = *(const bf16x8*)&sm.bstage[kt][(wn*4 + i)*512 + lane*8];
    #pragma unroll
    for (int mi = 0; mi < 4; ++mi)
      #pragma unroll
      for (int ni = 0; ni < 4; ++ni)
        acc[mi][ni] = __builtin_amdgcn_mfma_f32_16x16x32_bf16(
            a4[mi], b4[ni], acc[mi][ni], 0, 0, 0);
  }
  __syncthreads();   // done reading bstage before epi overwrite

  // ---- epilogue: 4 quarters of 64 rows via LDS, coalesced f32x4 stores ----
  const int lr0 = (lane >> 4) << 2;
  const int lc0 = wn*64 + (lane & 15);
  const size_t growbase = ((size_t)(z*MTB + mt)) << 8;
  #pragma unroll
  for (int h = 0; h < 4; ++h) {
    if (wm == h) {
      int tok[4];
      if (EPI == 1) {
        #pragma unroll
        for (int ni = 0; ni < 4; ++ni)
          tok[ni] = Ms[z*N_ + (nt<<7) + lc0 + ni*16];
      }
      #pragma unroll
      for (int mi = 0; mi < 4; ++mi) {
        #pragma unroll
        for (int ni = 0; ni < 4; ++ni) {
          int col = lc0 + ni*16;
          #pragma unroll
          for (int r = 0; r < 4; ++r) {
            int row = lr0 + mi*16 + r;              // 0..63 in quarter
            float v = acc[mi][ni][r];
            if (EPI == 1) {
              int rb = (mt<<8) + h*64 + row;        // row within batch
              int gc = (nt<<7) + col;
              int dd = rb - gc; if (dd < 0) dd = -dd; if (dd > 10) dd = 10;
              v -= (float)dd;
              if (tok[ni] == 0) v = -3.0e38f;
            }
            sm.epi[row*132 + col] = v;
          }
        }
      }
    }
    __syncthreads();
    {
      const int r0 = tid >> 5;            // 0..15
      const int c4 = (tid & 31) << 2;     // 0..124
      const int gc = (nt << 7) + c4;
      #pragma unroll
      for (int rr = r0; rr < 64; rr += 16) {
        size_t grow = growbase + h*64 + rr;
        if (gc + 3 < ncols) {
          f32x4 v = *(const f32x4*)&sm.epi[rr*132 + c4];
          if (NT) __builtin_nontemporal_store(v, (f32x4*)&out[grow*(size_t)ncols + gc]);
          else    *(f32x4*)&out[grow*(size_t)ncols + gc] = v;
        } else {
          #pragma unroll
          for (int e = 0; e < 4; ++e) {
            int c = gc + e;
            if (c < ncols) {
              float v = sm.epi[rr*132 + c4 + e];
              if (NT) __builtin_nontemporal_store(v, &out[grow*(size_t)ncols + c]);
              else    out[grow*(size_t)ncols + c] = v;
            }
          }
        }
      }
    }
    __syncthreads();
  }
}

// ================= KT=10 GEMM (128x128): stage-all-B, barrier-free ==========
template<int EPI, bool NT, bool PACKOUT, bool SWZ>
__global__ __launch_bounds__(256) void k_gemm10(
    const unsigned short* __restrict__ Ap, const unsigned short* __restrict__ Bp,
    float* __restrict__ out, unsigned short* __restrict__ outp,
    const float* __restrict__ resid, const int* __restrict__ Ms,
    int KTd, int MTB, int NTB, int ncols)
{
  __shared__ __align__(16) union {
    unsigned short bstage[10][4096];
    float epi[64*132];
  } sm;
  int nt, mt, z;
  if (SWZ) {
    int nwg = MTB * NTB;
    int wg = blockIdx.x;
    int cpx = nwg >> 3;
    int swz = (wg & 7) * cpx + (wg >> 3);
    mt = swz % MTB; nt = swz / MTB; z = 0;
  } else {
    nt = blockIdx.x; mt = blockIdx.y; z = blockIdx.z;
  }
  const int tid = threadIdx.x;
  const int wave = tid >> 6, lane = tid & 63;
  const int wm = wave >> 1, wn = wave & 1;
  const unsigned short* Ab = Ap + (size_t)(z*MTB + mt) * 10 * 4096;
  const unsigned short* Bb = Bp + (size_t)(z*NTB + nt) * 10 * 4096;

  #pragma unroll
  for (int kt = 0; kt < 10; ++kt) {
    const unsigned short* gb = Bb + kt*4096 + wave*1024 + lane*8;
    unsigned short* lb = &sm.bstage[kt][wave*1024];
    gl_lds16(gb,       lb);
    gl_lds16(gb + 512, lb + 512);
  }

  const unsigned short* ga = Ab + (wm*4)*512 + lane*8;
  bf16x8 aA[4], aB[4];
  #pragma unroll
  for (int i = 0; i < 4; ++i) aA[i] = *(const bf16x8*)(ga + 0*4096 + i*512);
  #pragma unroll
  for (int i = 0; i < 4; ++i) aB[i] = *(const bf16x8*)(ga + 1*4096 + i*512);

  __syncthreads();

  f32x4 acc[4][4] = {};
  auto mfma_step = [&](int kt, const bf16x8* a) {
    bf16x8 bfr[4];
    #pragma unroll
    for (int i = 0; i < 4; ++i)
      bfr[i] = *(const bf16x8*)&sm.bstage[kt][(wn*4 + i)*512 + lane*8];
    #pragma unroll
    for (int mi = 0; mi < 4; ++mi)
      #pragma unroll
      for (int ni = 0; ni < 4; ++ni)
        acc[mi][ni] = __builtin_amdgcn_mfma_f32_16x16x32_bf16(
            a[mi], bfr[ni], acc[mi][ni], 0, 0, 0);
  };
  auto loadA = [&](int kt, bf16x8* d) {
    #pragma unroll
    for (int i = 0; i < 4; ++i) d[i] = *(const bf16x8*)(ga + kt*4096 + i*512);
  };

  #pragma unroll
  for (int kt = 0; kt < 10; kt += 2) {
    mfma_step(kt, aA);
    if (kt + 2 < 10) loadA(kt + 2, aA);
    mfma_step(kt + 1, aB);
    if (kt + 3 < 10) loadA(kt + 3, aB);
  }

  __syncthreads();

  const int lr0 = (lane >> 4) << 2;
  const int lc0 = wn*64 + (lane & 15);
  const size_t growbase = ((size_t)(z*MTB + mt)) << 7;
  #pragma unroll
  for (int h = 0; h < 2; ++h) {
    if (wm == h) {
      int tok[4];
      if (EPI == 1) {
        #pragma unroll
        for (int ni = 0; ni < 4; ++ni)
          tok[ni] = Ms[z*N_ + (nt<<7) + lc0 + ni*16];
      }
      #pragma unroll
      for (int mi = 0; mi < 4; ++mi) {
        #pragma unroll
        for (int ni = 0; ni < 4; ++ni) {
          int col = lc0 + ni*16;
          #pragma unroll
          for (int r = 0; r < 4; ++r) {
            int row = lr0 + mi*16 + r;
            float v = acc[mi][ni][r];
            if (EPI == 1) {
              int rb = (mt<<7) + h*64 + row;
              int gc = (nt<<7) + col;
              int dd = rb - gc; if (dd < 0) dd = -dd; if (dd > 10) dd = 10;
              v -= (float)dd;
              if (tok[ni] == 0) v = -3.0e38f;
            }
            sm.epi[row*132 + col] = v;
          }
        }
      }
    }
    __syncthreads();
    if (PACKOUT) {
      int prow = tid >> 2, pktq = tid & 3;
      int ktd = nt*4 + pktq;
      if (ktd < KTd) {
        int grl = h*64 + prow;
        int fb = grl >> 4, rl = grl & 15;
        size_t cbase = ((size_t)((z*MTB + mt)*KTd + ktd))*4096 + fb*512 + rl*8;
        #pragma unroll
        for (int oct = 0; oct < 4; ++oct) {
          unsigned short v[8];
          #pragma unroll
          for (int e = 0; e < 8; ++e)
            v[e] = f2bf(sm.epi[prow*132 + pktq*32 + oct*8 + e]);
          ushort4* o = (ushort4*)&outp[cbase + oct*128];
          o[0] = make_ushort4(v[0],v[1],v[2],v[3]);
          o[1] = make_ushort4(v[4],v[5],v[6],v[7]);
        }
      }
    } else {
      const int r0 = tid >> 5;
      const int c4 = (tid & 31) << 2;
      const int gc = (nt << 7) + c4;
      #pragma unroll
      for (int rr = r0; rr < 64; rr += 8) {
        size_t grow = growbase + h*64 + rr;
        if (gc + 3 < ncols) {
          f32x4 v = *(const f32x4*)&sm.epi[rr*132 + c4];
          if (EPI == 2) v += *(const f32x4*)&resid[grow*(size_t)ncols + gc];
          if (NT) __builtin_nontemporal_store(v, (f32x4*)&out[grow*(size_t)ncols + gc]);
          else    *(f32x4*)&out[grow*(size_t)ncols + gc] = v;
        } else {
          #pragma unroll
          for (int e = 0; e < 4; ++e) {
            int c = gc + e;
            if (c < ncols) {
              float v = sm.epi[rr*132 + c4 + e];
              if (EPI == 2) v += resid[grow*(size_t)ncols + c];
              if (NT) __builtin_nontemporal_store(v, &out[grow*(size_t)ncols + c]);
              else    out[grow*(size_t)ncols + c] = v;
            }
          }
        }
      }
    }
    __syncthreads();
  }
}

// ===== KT=64 GEMM (C = A@X): double-buffered + PACKOUT ====
__global__ __launch_bounds__(256) void k_gemm64(
    const unsigned short* __restrict__ Ap, const unsigned short* __restrict__ Bp,
    unsigned short* __restrict__ outp, int KT, int KTd, int MTB, int NTB)
{
  __shared__ __align__(16) union {
    unsigned short stage[2][2][4096];
    float epi[64*132];
  } sm;
  const int nt = blockIdx.x, mt = blockIdx.y, z = blockIdx.z;
  const int tid = threadIdx.x;
  const int wave = tid >> 6, lane = tid & 63;
  const int wm = wave >> 1, wn = wave & 1;
  const unsigned short* Ab = Ap + (size_t)(z*MTB + mt) * KT * 4096;
  const unsigned short* Bb = Bp + (size_t)(z*NTB + nt) * KT * 4096;
  f32x4 acc[4][4] = {};

  auto stage = [&](int s, int kt) {
    const unsigned short* ga = Ab + kt*4096 + wave*1024 + lane*8;
    const unsigned short* gb = Bb + kt*4096 + wave*1024 + lane*8;
    unsigned short* la = &sm.stage[s][0][wave*1024];
    unsigned short* lb = &sm.stage[s][1][wave*1024];
    gl_lds16(ga,       la);
    gl_lds16(ga + 512, la + 512);
    gl_lds16(gb,       lb);
    gl_lds16(gb + 512, lb + 512);
  };

  stage(0, 0);
  __syncthreads();
  for (int kt = 0; kt < KT; ++kt) {
    int cur = kt & 1;
    if (kt + 1 < KT) stage(cur ^ 1, kt + 1);
    bf16x8 af[4], bfr[4];
    #pragma unroll
    for (int i = 0; i < 4; ++i)
      af[i] = *(const bf16x8*)&sm.stage[cur][0][(wm*4 + i)*512 + lane*8];
    #pragma unroll
    for (int i = 0; i < 4; ++i)
      bfr[i] = *(const bf16x8*)&sm.stage[cur][1][(wn*4 + i)*512 + lane*8];
    #pragma unroll
    for (int mi = 0; mi < 4; ++mi)
      #pragma unroll
      for (int ni = 0; ni < 4; ++ni)
        acc[mi][ni] = __builtin_amdgcn_mfma_f32_16x16x32_bf16(
            af[mi], bfr[ni], acc[mi][ni], 0, 0, 0);
    __syncthreads();
  }

  const int lr0 = (lane >> 4) << 2;
  const int lc0 = wn*64 + (lane & 15);
  #pragma unroll
  for (int h = 0; h < 2; ++h) {
    if (wm == h) {
      #pragma unroll
      for (int mi = 0; mi < 4; ++mi)
        #pragma unroll
        for (int ni = 0; ni < 4; ++ni) {
          int col = lc0 + ni*16;
          #pragma unroll
          for (int r = 0; r < 4; ++r)
            sm.epi[(lr0 + mi*16 + r)*132 + col] = acc[mi][ni][r];
        }
    }
    __syncthreads();
    {
      int prow = tid >> 2, pktq = tid & 3;
      int ktd = nt*4 + pktq;
      if (ktd < KTd) {
        int grl = h*64 + prow;
        int fb = grl >> 4, rl = grl & 15;
        size_t cbase = ((size_t)((z*MTB + mt)*KTd + ktd))*4096 + fb*512 + rl*8;
        #pragma unroll
        for (int oct = 0; oct < 4; ++oct) {
          unsigned short v[8];
          #pragma unroll
          for (int e = 0; e < 8; ++e)
            v[e] = f2bf(sm.epi[prow*132 + pktq*32 + oct*8 + e]);
          ushort4* o = (ushort4*)&outp[cbase + oct*128];
          o[0] = make_ushort4(v[0],v[1],v[2],v[3]);
          o[1] = make_ushort4(v[4],v[5],v[6],v[7]);
        }
      }
    }
    __syncthreads();
  }
}

// ---- row softmax: reg-held row, 2 barriers, f32x4 NT out + packed A frags ----
__global__ __launch_bounds__(256) void k_softmax(float* __restrict__ S,
    unsigned short* __restrict__ Apk) {
  __shared__ float w[N_];        // e-values (for the pack)
  __shared__ float redm[4], reds[4];
  int row = blockIdx.x, tid = threadIdx.x;
  float* sr = S + (size_t)row * N_;
  f32x4 v0 = ((const f32x4*)sr)[tid];
  f32x4 v1 = ((const f32x4*)sr)[tid + 256];
  float vmax = fmaxf(fmaxf(fmaxf(v0.x, v0.y), fmaxf(v0.z, v0.w)),
                     fmaxf(fmaxf(v1.x, v1.y), fmaxf(v1.z, v1.w)));
  #pragma unroll
  for (int off = 32; off; off >>= 1) vmax = fmaxf(vmax, __shfl_down(vmax, off, 64));
  if ((tid & 63) == 0) redm[tid >> 6] = vmax;
  __syncthreads();
  vmax = fmaxf(fmaxf(redm[0], redm[1]), fmaxf(redm[2], redm[3]));
  f32x4 e0, e1;
  e0.x = __expf(v0.x - vmax); e0.y = __expf(v0.y - vmax);
  e0.z = __expf(v0.z - vmax); e0.w = __expf(v0.w - vmax);
  e1.x = __expf(v1.x - vmax); e1.y = __expf(v1.y - vmax);
  e1.z = __expf(v1.z - vmax); e1.w = __expf(v1.w - vmax);
  ((f32x4*)w)[tid] = e0;
  ((f32x4*)w)[tid + 256] = e1;
  float vsum = (e0.x + e0.y + e0.z + e0.w) + (e1.x + e1.y + e1.z + e1.w);
  #pragma unroll
  for (int off = 32; off; off >>= 1) vsum += __shfl_down(vsum, off, 64);
  if ((tid & 63) == 0) reds[tid >> 6] = vsum;
  __syncthreads();               // orders reds AND w(e) writes
  float inv = 1.f / ((reds[0] + reds[1]) + (reds[2] + reds[3]));
  f32x4 o0 = e0 * inv, o1 = e1 * inv;
  __builtin_nontemporal_store(o0, &((f32x4*)sr)[tid]);
  __builtin_nontemporal_store(o1, &((f32x4*)sr)[tid + 256]);
  int kt = tid >> 2, j = tid & 3;
  int m0 = kt*32 + j*8;
  int fb = (row >> 4) & 7, rl = row & 15;
  unsigned short v[8];
  #pragma unroll
  for (int e = 0; e < 8; ++e) v[e] = f2bf(w[m0 + e] * inv);
  size_t off_ = ((size_t)((row >> 7)*64 + kt))*4096 + fb*512 + rl*8 + j*128;
  ushort4* o = (ushort4*)&Apk[off_];
  o[0] = make_ushort4(v[0],v[1],v[2],v[3]);
  o[1] = make_ushort4(v[4],v[5],v[6],v[7]);
}

// ---- LayerNorm on H + fused Hp fragment pack ----
__global__ __launch_bounds__(320) void k_ln_pack(const float* __restrict__ H,
    const float* __restrict__ gamma, const float* __restrict__ beta,
    unsigned short* __restrict__ Hp) {
  __shared__ float red[5];
  __shared__ float hs[320];
  int row = blockIdx.x, tid = threadIdx.x;
  float h = (tid < D_) ? H[(size_t)row*D_ + tid] : 0.f;
  float s = h;
  #pragma unroll
  for (int off = 32; off; off >>= 1) s += __shfl_down(s, off, 64);
  if ((tid & 63) == 0) red[tid >> 6] = s;
  __syncthreads();
  float mu = (red[0]+red[1]+red[2]+red[3]+red[4]) * (1.f/(float)D_);
  float dv = (tid < D_) ? (h - mu) : 0.f;
  float s2 = dv * dv;
  #pragma unroll
  for (int off = 32; off; off >>= 1) s2 += __shfl_down(s2, off, 64);
  __syncthreads();
  if ((tid & 63) == 0) red[tid >> 6] = s2;
  __syncthreads();
  float var = (red[0]+red[1]+red[2]+red[3]+red[4]) * (1.f/(float)D_);
  float rstd = rsqrtf(var + 1e-5f);
  hs[tid] = (tid < D_) ? (dv * rstd * gamma[tid] + beta[tid]) : 0.f;
  __syncthreads();
  if (tid < 40) {
    int kt = tid >> 2, j = tid & 3;
    int tile = row >> 7, fb = (row >> 4) & 7, rl = row & 15;
    unsigned short v[8];
    #pragma unroll
    for (int e = 0; e < 8; ++e) v[e] = f2bf(hs[kt*32 + j*8 + e]);
    size_t off_ = ((size_t)(tile*10 + kt))*4096 + fb*512 + rl*8 + j*128;
    ushort4* o = (ushort4*)&Hp[off_];
    o[0] = make_ushort4(v[0],v[1],v[2],v[3]);
    o[1] = make_ushort4(v[4],v[5],v[6],v[7]);
  }
}

extern "C" void kernel_launch(void* const* d_in, const int* in_sizes, int n_in,
                              void* d_out, int out_size, void* d_ws, size_t ws_size,
                              hipStream_t stream) {
  const int*   M_s   = (const int*)d_in[0];
  const float* E_v   = (const float*)d_in[1];
  const float* E_y   = (const float*)d_in[2];
  const float* W_A   = (const float*)d_in[3];
  const float* W_O   = (const float*)d_in[4];
  const float* gamma = (const float*)d_in[5];
  const float* beta  = (const float*)d_in[6];

  float* Yl = (float*)d_out;                       // [8192, 20000]
  float* A  = Yl + (size_t)ROWS * Y_;              // [8192, 2048] (scores -> softmax in place)

  float* X  = (float*)d_ws;                        // [8192,300]
  float* QW = X  + (size_t)ROWS * D_;              // region free (packed path)
  float* H  = QW + (size_t)ROWS * D_;              // [8192,300]
  unsigned short* Ep = (unsigned short*)(H + (size_t)ROWS * D_); // packed E_y (d_ws)
  // Hpk overlays X in d_ws (X dead after residual GEMM); must NOT live in the
  // Yl region the logits GEMM writes (round-8 NaN lesson).
  unsigned short* Hpk = (unsigned short*)X;

  // packed temporaries in the dead tail of the Yl region — all consumed before
  // the final logits GEMM launches (stream-ordered).
  unsigned short* scr = (unsigned short*)(Yl + 100000000ull);
  unsigned short* Xp  = scr;                       // 2,621,440 ush
  unsigned short* QWp = Xp  + 2621440;             // 2,621,440
  unsigned short* Wap = QWp + 2621440;             //   122,880
  unsigned short* Wop = Wap + 122880;              //   122,880
  unsigned short* XTp = Wop + 122880;              // 3,145,728
  unsigned short* Cp  = XTp + 3145728;             // 2,621,440
  unsigned short* Apk = Cp  + 2621440;             // 16,777,216

  k_gather_pack<<<ROWS, 256, 0, stream>>>(M_s, E_v, X, Xp);
  k_packT <<<dim3(3*10,1), 256, 0, stream>>>(W_A, Wap, D_, D_, 10, 0, 0);
  // QW = X @ W_A -> packed QWp (epilogue fusion)
  k_gemm10<0,false,true,false><<<dim3(3,64,1), 256, 0, stream>>>(
      Xp, Wap, nullptr, QWp, nullptr, nullptr, 10, 64, 3, D_);
  // S = QW @ X^T - dist, masked  (256x128 tile, 8 waves, LDS epilogue)
  k_gemm256<1,false,false><<<dim3(16,8,4), 512, 0, stream>>>(
      QWp, Xp, A, M_s, 8, 16, N_);
  k_softmax<<<ROWS, 256, 0, stream>>>(A, Apk);
  k_packT <<<dim3(3*64,4), 256, 0, stream>>>(X, XTp, N_, D_, 64, (size_t)N_*D_, 192);
  // C = A @ X -> packed Cp (KT=64 dbuf)
  k_gemm64<<<dim3(3,16,4), 256, 0, stream>>>(Apk, XTp, Cp, 64, 10, 16, 3);
  k_packT <<<dim3(3*10,1), 256, 0, stream>>>(W_O, Wop, D_, D_, 10, 0, 0);
  // H = C @ W_O + X
  k_gemm10<2,false,false,false><<<dim3(3,64,1), 256, 0, stream>>>(
      Cp, Wop, H, nullptr, X, nullptr, 0, 64, 3, D_);
  k_ln_pack<<<ROWS, 320, 0, stream>>>(H, gamma, beta, Hpk);
  k_pack  <<<157*10, 256, 0, stream>>>(E_y, Ep, Y_, D_, 10);
  // Yl = Hn @ E_y^T  (256x128 tile, 8 waves, XCD swizzle, LDS epi + NT f32x4)
  k_gemm256<0,true,true><<<dim3(157*32,1,1), 512, 0, stream>>>(
      Hpk, Ep, Yl, nullptr, 32, 157, Y_);
}

// Round 18
// 373.673 us; speedup vs baseline: 1.1414x; 1.0003x over previous
//
#include <hip/hip_runtime.h>
#include <hip/hip_bf16.h>

#define B_ 4
#define N_ 2048
#define D_ 300
#define Y_ 20000
#define ROWS (B_*N_)   // 8192

typedef __attribute__((ext_vector_type(8))) short bf16x8;
typedef __attribute__((ext_vector_type(4))) float f32x4;

__device__ __forceinline__ unsigned short f2bf(float f) {  // RNE f32->bf16
  unsigned u = __float_as_uint(f);
  unsigned r = (u + 0x7FFFu + ((u >> 16) & 1u)) >> 16;
  return (unsigned short)r;
}

__device__ __forceinline__ void gl_lds16(const unsigned short* g, unsigned short* l) {
  __builtin_amdgcn_global_load_lds(
      (const __attribute__((address_space(1))) void*)g,
      (__attribute__((address_space(3))) void*)l, 16, 0, 0);
}

// ---- X = E_v[M_s] (f32) + fused Xp fragment pack ----
__global__ __launch_bounds__(256) void k_gather_pack(const int* __restrict__ M_s,
    const float* __restrict__ E_v, float* __restrict__ X,
    unsigned short* __restrict__ Xp) {
  __shared__ float xs[320];
  int row = blockIdx.x, tid = threadIdx.x;
  int tok = M_s[row];
  const float* src = E_v + (size_t)tok * D_;
  for (int d = tid; d < 320; d += 256) xs[d] = (d < D_) ? src[d] : 0.f;
  __syncthreads();
  float* dst = X + (size_t)row * D_;
  for (int d = tid; d < D_; d += 256) dst[d] = xs[d];
  if (tid < 40) {
    int kt = tid >> 2, j = tid & 3;
    int tile = row >> 7, fb = (row >> 4) & 7, rl = row & 15;
    unsigned short v[8];
    #pragma unroll
    for (int e = 0; e < 8; ++e) v[e] = f2bf(xs[kt*32 + j*8 + e]);
    size_t off_ = ((size_t)(tile*10 + kt))*4096 + fb*512 + rl*8 + j*128;
    ushort4* o = (ushort4*)&Xp[off_];
    o[0] = make_ushort4(v[0],v[1],v[2],v[3]);
    o[1] = make_ushort4(v[4],v[5],v[6],v[7]);
  }
}

// ---- pack f32 [nrows,ncols] row-major -> bf16 MFMA fragment chunks ----
__global__ __launch_bounds__(256) void k_pack(const float* __restrict__ src,
    unsigned short* __restrict__ dst, int nrows, int ncols, int KT) {
  int chunk = blockIdx.x;
  int tile = chunk / KT, kt = chunk - tile*KT;
  size_t obase = (size_t)chunk * 4096;
  #pragma unroll
  for (int p = 0; p < 2; ++p) {
    int idx = p*256 + threadIdx.x;
    int fb = idx >> 6, l = idx & 63;
    int row = tile*128 + fb*16 + (l & 15);
    int gk = kt*32 + (l >> 4)*8;
    unsigned short v[8];
    #pragma unroll
    for (int e = 0; e < 8; ++e) {
      int k = gk + e;
      float f = (row < nrows && k < ncols) ? src[(size_t)row*ncols + k] : 0.f;
      v[e] = f2bf(f);
    }
    ushort4* o = (ushort4*)&dst[obase + (size_t)idx*8];
    o[0] = make_ushort4(v[0],v[1],v[2],v[3]);
    o[1] = make_ushort4(v[4],v[5],v[6],v[7]);
  }
}

// ---- transposing pack via LDS (coalesced source reads) ----
__global__ __launch_bounds__(256) void k_packT(const float* __restrict__ src,
    unsigned short* __restrict__ dst, int src_rows, int src_cols, int KT,
    size_t src_bstride, size_t dst_bchunks) {
  __shared__ float ls[32*133];
  int chunk = blockIdx.x, b = blockIdx.y, tid = threadIdx.x;
  const float* s = src + (size_t)b * src_bstride;
  unsigned short* d = dst + ((size_t)b * dst_bchunks + chunk) * 4096;
  int tile = chunk / KT, kt = chunk - tile*KT;
  int c0 = tile*128, k0 = kt*32;
  for (int i = tid; i < 4096; i += 256) {
    int r = i >> 7, c = i & 127;
    int sr = k0 + r, sc = c0 + c;
    ls[r*133 + c] = (sr < src_rows && sc < src_cols) ? s[(size_t)sr*src_cols + sc] : 0.f;
  }
  __syncthreads();
  #pragma unroll
  for (int p = 0; p < 2; ++p) {
    int idx = p*256 + tid;
    int fb = idx >> 6, l = idx & 63;
    int r = fb*16 + (l & 15);
    int kl = (l >> 4)*8;
    unsigned short v[8];
    #pragma unroll
    for (int e = 0; e < 8; ++e) v[e] = f2bf(ls[(kl + e)*133 + r]);
    ushort4* o = (ushort4*)&d[(size_t)idx*8];
    o[0] = make_ushort4(v[0],v[1],v[2],v[3]);
    o[1] = make_ushort4(v[4],v[5],v[6],v[7]);
  }
}

// ========== 256x128-tile KT=10 GEMM: 8 waves, stage-all-B, barrier-free =====
// R14-verified structure: LDS-staged epilogue (coalesced f32x4 stores).
// NT stores MUST go through the LDS transpose — scalar NT fragments bypass L2
// write-combining and regress 51us (round-16 lesson).
// EPI 0: plain; 1: score (-dist, pad mask).  NT: nontemporal.  SWZ: XCD swizzle.
template<int EPI, bool NT, bool SWZ>
__global__ __launch_bounds__(512, 4) void k_gemm256(
    const unsigned short* __restrict__ Ap, const unsigned short* __restrict__ Bp,
    float* __restrict__ out, const int* __restrict__ Ms,
    int MTB, int NTB, int ncols)
{
  __shared__ __align__(16) union {
    unsigned short bstage[10][4096];    // 80 KB (read-only after barrier)
    float epi[64*132];                  // epilogue quarter tile
  } sm;
  int nt, mt, z;
  if (SWZ) {
    int wg = blockIdx.x;
    int cpx = (MTB*NTB) >> 3;           // caller guarantees grid%8==0
    int swz = (wg & 7)*cpx + (wg >> 3);
    mt = swz % MTB; nt = swz / MTB; z = 0;
  } else { nt = blockIdx.x; mt = blockIdx.y; z = blockIdx.z; }
  const int tid = threadIdx.x;
  const int wave = tid >> 6, lane = tid & 63;
  const int wm = wave >> 1, wn = wave & 1;          // wm 0..3, wn 0..1
  const int mtile2 = (z*MTB + mt)*2 + (wm >> 1);    // which 128-row A tile
  const unsigned short* Ab = Ap + (size_t)mtile2 * 10 * 4096;
  const unsigned short* Bb = Bp + (size_t)(z*NTB + nt) * 10 * 4096;

  // stage all 10 B chunks: wave w covers 512B segment of each 8KB chunk
  #pragma unroll
  for (int kt = 0; kt < 10; ++kt)
    gl_lds16(Bb + kt*4096 + wave*512 + lane*8, &sm.bstage[kt][wave*512]);

  const unsigned short* ga = Ab + ((wm & 1)*4)*512 + lane*8;
  __syncthreads();   // vmcnt(0) drain == all B staged

  f32x4 acc[4][4] = {};
  #pragma unroll
  for (int kt = 0; kt < 10; ++kt) {
    bf16x8 a4[4], b4[4];
    #pragma unroll
    for (int i = 0; i < 4; ++i)
      a4[i] = *(const bf16x8*)(ga + kt*4096 + i*512);
    #pragma unroll
    for (int i = 0; i < 4; ++i)
      b4[i] = *(const bf16x8*)&sm.bstage[kt][(wn*4 + i)*512 + lane*8];
    #pragma unroll
    for (int mi = 0; mi < 4; ++mi)
      #pragma unroll
      for (int ni = 0; ni < 4; ++ni)
        acc[mi][ni] = __builtin_amdgcn_mfma_f32_16x16x32_bf16(
            a4[mi], b4[ni], acc[mi][ni], 0, 0, 0);
  }
  __syncthreads();   // done reading bstage before epi overwrite

  // ---- epilogue: 4 quarters of 64 rows via LDS, coalesced f32x4 stores ----
  const int lr0 = (lane >> 4) << 2;
  const int lc0 = wn*64 + (lane & 15);
  const size_t growbase = ((size_t)(z*MTB + mt)) << 8;
  #pragma unroll
  for (int h = 0; h < 4; ++h) {
    if (wm == h) {
      int tok[4];
      if (EPI == 1) {
        #pragma unroll
        for (int ni = 0; ni < 4; ++ni)
          tok[ni] = Ms[z*N_ + (nt<<7) + lc0 + ni*16];
      }
      #pragma unroll
      for (int mi = 0; mi < 4; ++mi) {
        #pragma unroll
        for (int ni = 0; ni < 4; ++ni) {
          int col = lc0 + ni*16;
          #pragma unroll
          for (int r = 0; r < 4; ++r) {
            int row = lr0 + mi*16 + r;              // 0..63 in quarter
            float v = acc[mi][ni][r];
            if (EPI == 1) {
              int rb = (mt<<8) + h*64 + row;        // row within batch
              int gc = (nt<<7) + col;
              int dd = rb - gc; if (dd < 0) dd = -dd; if (dd > 10) dd = 10;
              v -= (float)dd;
              if (tok[ni] == 0) v = -3.0e38f;
            }
            sm.epi[row*132 + col] = v;
          }
        }
      }
    }
    __syncthreads();
    {
      const int r0 = tid >> 5;            // 0..15
      const int c4 = (tid & 31) << 2;     // 0..124
      const int gc = (nt << 7) + c4;
      #pragma unroll
      for (int rr = r0; rr < 64; rr += 16) {
        size_t grow = growbase + h*64 + rr;
        if (gc + 3 < ncols) {
          f32x4 v = *(const f32x4*)&sm.epi[rr*132 + c4];
          if (NT) __builtin_nontemporal_store(v, (f32x4*)&out[grow*(size_t)ncols + gc]);
          else    *(f32x4*)&out[grow*(size_t)ncols + gc] = v;
        } else {
          #pragma unroll
          for (int e = 0; e < 4; ++e) {
            int c = gc + e;
            if (c < ncols) {
              float v = sm.epi[rr*132 + c4 + e];
              if (NT) __builtin_nontemporal_store(v, &out[grow*(size_t)ncols + c]);
              else    out[grow*(size_t)ncols + c] = v;
            }
          }
        }
      }
    }
    __syncthreads();
  }
}

// ================= KT=10 GEMM (128x128): stage-all-B, barrier-free ==========
template<int EPI, bool NT, bool PACKOUT, bool SWZ>
__global__ __launch_bounds__(256) void k_gemm10(
    const unsigned short* __restrict__ Ap, const unsigned short* __restrict__ Bp,
    float* __restrict__ out, unsigned short* __restrict__ outp,
    const float* __restrict__ resid, const int* __restrict__ Ms,
    int KTd, int MTB, int NTB, int ncols)
{
  __shared__ __align__(16) union {
    unsigned short bstage[10][4096];
    float epi[64*132];
  } sm;
  int nt, mt, z;
  if (SWZ) {
    int nwg = MTB * NTB;
    int wg = blockIdx.x;
    int cpx = nwg >> 3;
    int swz = (wg & 7) * cpx + (wg >> 3);
    mt = swz % MTB; nt = swz / MTB; z = 0;
  } else {
    nt = blockIdx.x; mt = blockIdx.y; z = blockIdx.z;
  }
  const int tid = threadIdx.x;
  const int wave = tid >> 6, lane = tid & 63;
  const int wm = wave >> 1, wn = wave & 1;
  const unsigned short* Ab = Ap + (size_t)(z*MTB + mt) * 10 * 4096;
  const unsigned short* Bb = Bp + (size_t)(z*NTB + nt) * 10 * 4096;

  #pragma unroll
  for (int kt = 0; kt < 10; ++kt) {
    const unsigned short* gb = Bb + kt*4096 + wave*1024 + lane*8;
    unsigned short* lb = &sm.bstage[kt][wave*1024];
    gl_lds16(gb,       lb);
    gl_lds16(gb + 512, lb + 512);
  }

  const unsigned short* ga = Ab + (wm*4)*512 + lane*8;
  bf16x8 aA[4], aB[4];
  #pragma unroll
  for (int i = 0; i < 4; ++i) aA[i] = *(const bf16x8*)(ga + 0*4096 + i*512);
  #pragma unroll
  for (int i = 0; i < 4; ++i) aB[i] = *(const bf16x8*)(ga + 1*4096 + i*512);

  __syncthreads();

  f32x4 acc[4][4] = {};
  auto mfma_step = [&](int kt, const bf16x8* a) {
    bf16x8 bfr[4];
    #pragma unroll
    for (int i = 0; i < 4; ++i)
      bfr[i] = *(const bf16x8*)&sm.bstage[kt][(wn*4 + i)*512 + lane*8];
    #pragma unroll
    for (int mi = 0; mi < 4; ++mi)
      #pragma unroll
      for (int ni = 0; ni < 4; ++ni)
        acc[mi][ni] = __builtin_amdgcn_mfma_f32_16x16x32_bf16(
            a[mi], bfr[ni], acc[mi][ni], 0, 0, 0);
  };
  auto loadA = [&](int kt, bf16x8* d) {
    #pragma unroll
    for (int i = 0; i < 4; ++i) d[i] = *(const bf16x8*)(ga + kt*4096 + i*512);
  };

  #pragma unroll
  for (int kt = 0; kt < 10; kt += 2) {
    mfma_step(kt, aA);
    if (kt + 2 < 10) loadA(kt + 2, aA);
    mfma_step(kt + 1, aB);
    if (kt + 3 < 10) loadA(kt + 3, aB);
  }

  __syncthreads();

  const int lr0 = (lane >> 4) << 2;
  const int lc0 = wn*64 + (lane & 15);
  const size_t growbase = ((size_t)(z*MTB + mt)) << 7;
  #pragma unroll
  for (int h = 0; h < 2; ++h) {
    if (wm == h) {
      int tok[4];
      if (EPI == 1) {
        #pragma unroll
        for (int ni = 0; ni < 4; ++ni)
          tok[ni] = Ms[z*N_ + (nt<<7) + lc0 + ni*16];
      }
      #pragma unroll
      for (int mi = 0; mi < 4; ++mi) {
        #pragma unroll
        for (int ni = 0; ni < 4; ++ni) {
          int col = lc0 + ni*16;
          #pragma unroll
          for (int r = 0; r < 4; ++r) {
            int row = lr0 + mi*16 + r;
            float v = acc[mi][ni][r];
            if (EPI == 1) {
              int rb = (mt<<7) + h*64 + row;
              int gc = (nt<<7) + col;
              int dd = rb - gc; if (dd < 0) dd = -dd; if (dd > 10) dd = 10;
              v -= (float)dd;
              if (tok[ni] == 0) v = -3.0e38f;
            }
            sm.epi[row*132 + col] = v;
          }
        }
      }
    }
    __syncthreads();
    if (PACKOUT) {
      int prow = tid >> 2, pktq = tid & 3;
      int ktd = nt*4 + pktq;
      if (ktd < KTd) {
        int grl = h*64 + prow;
        int fb = grl >> 4, rl = grl & 15;
        size_t cbase = ((size_t)((z*MTB + mt)*KTd + ktd))*4096 + fb*512 + rl*8;
        #pragma unroll
        for (int oct = 0; oct < 4; ++oct) {
          unsigned short v[8];
          #pragma unroll
          for (int e = 0; e < 8; ++e)
            v[e] = f2bf(sm.epi[prow*132 + pktq*32 + oct*8 + e]);
          ushort4* o = (ushort4*)&outp[cbase + oct*128];
          o[0] = make_ushort4(v[0],v[1],v[2],v[3]);
          o[1] = make_ushort4(v[4],v[5],v[6],v[7]);
        }
      }
    } else {
      const int r0 = tid >> 5;
      const int c4 = (tid & 31) << 2;
      const int gc = (nt << 7) + c4;
      #pragma unroll
      for (int rr = r0; rr < 64; rr += 8) {
        size_t grow = growbase + h*64 + rr;
        if (gc + 3 < ncols) {
          f32x4 v = *(const f32x4*)&sm.epi[rr*132 + c4];
          if (EPI == 2) v += *(const f32x4*)&resid[grow*(size_t)ncols + gc];
          if (NT) __builtin_nontemporal_store(v, (f32x4*)&out[grow*(size_t)ncols + gc]);
          else    *(f32x4*)&out[grow*(size_t)ncols + gc] = v;
        } else {
          #pragma unroll
          for (int e = 0; e < 4; ++e) {
            int c = gc + e;
            if (c < ncols) {
              float v = sm.epi[rr*132 + c4 + e];
              if (EPI == 2) v += resid[grow*(size_t)ncols + c];
              if (NT) __builtin_nontemporal_store(v, &out[grow*(size_t)ncols + c]);
              else    out[grow*(size_t)ncols + c] = v;
            }
          }
        }
      }
    }
    __syncthreads();
  }
}

// ===== KT=64 GEMM (C = A@X): double-buffered + PACKOUT ====
__global__ __launch_bounds__(256) void k_gemm64(
    const unsigned short* __restrict__ Ap, const unsigned short* __restrict__ Bp,
    unsigned short* __restrict__ outp, int KT, int KTd, int MTB, int NTB)
{
  __shared__ __align__(16) union {
    unsigned short stage[2][2][4096];
    float epi[64*132];
  } sm;
  const int nt = blockIdx.x, mt = blockIdx.y, z = blockIdx.z;
  const int tid = threadIdx.x;
  const int wave = tid >> 6, lane = tid & 63;
  const int wm = wave >> 1, wn = wave & 1;
  const unsigned short* Ab = Ap + (size_t)(z*MTB + mt) * KT * 4096;
  const unsigned short* Bb = Bp + (size_t)(z*NTB + nt) * KT * 4096;
  f32x4 acc[4][4] = {};

  auto stage = [&](int s, int kt) {
    const unsigned short* ga = Ab + kt*4096 + wave*1024 + lane*8;
    const unsigned short* gb = Bb + kt*4096 + wave*1024 + lane*8;
    unsigned short* la = &sm.stage[s][0][wave*1024];
    unsigned short* lb = &sm.stage[s][1][wave*1024];
    gl_lds16(ga,       la);
    gl_lds16(ga + 512, la + 512);
    gl_lds16(gb,       lb);
    gl_lds16(gb + 512, lb + 512);
  };

  stage(0, 0);
  __syncthreads();
  for (int kt = 0; kt < KT; ++kt) {
    int cur = kt & 1;
    if (kt + 1 < KT) stage(cur ^ 1, kt + 1);
    bf16x8 af[4], bfr[4];
    #pragma unroll
    for (int i = 0; i < 4; ++i)
      af[i] = *(const bf16x8*)&sm.stage[cur][0][(wm*4 + i)*512 + lane*8];
    #pragma unroll
    for (int i = 0; i < 4; ++i)
      bfr[i] = *(const bf16x8*)&sm.stage[cur][1][(wn*4 + i)*512 + lane*8];
    #pragma unroll
    for (int mi = 0; mi < 4; ++mi)
      #pragma unroll
      for (int ni = 0; ni < 4; ++ni)
        acc[mi][ni] = __builtin_amdgcn_mfma_f32_16x16x32_bf16(
            af[mi], bfr[ni], acc[mi][ni], 0, 0, 0);
    __syncthreads();
  }

  const int lr0 = (lane >> 4) << 2;
  const int lc0 = wn*64 + (lane & 15);
  #pragma unroll
  for (int h = 0; h < 2; ++h) {
    if (wm == h) {
      #pragma unroll
      for (int mi = 0; mi < 4; ++mi)
        #pragma unroll
        for (int ni = 0; ni < 4; ++ni) {
          int col = lc0 + ni*16;
          #pragma unroll
          for (int r = 0; r < 4; ++r)
            sm.epi[(lr0 + mi*16 + r)*132 + col] = acc[mi][ni][r];
        }
    }
    __syncthreads();
    {
      int prow = tid >> 2, pktq = tid & 3;
      int ktd = nt*4 + pktq;
      if (ktd < KTd) {
        int grl = h*64 + prow;
        int fb = grl >> 4, rl = grl & 15;
        size_t cbase = ((size_t)((z*MTB + mt)*KTd + ktd))*4096 + fb*512 + rl*8;
        #pragma unroll
        for (int oct = 0; oct < 4; ++oct) {
          unsigned short v[8];
          #pragma unroll
          for (int e = 0; e < 8; ++e)
            v[e] = f2bf(sm.epi[prow*132 + pktq*32 + oct*8 + e]);
          ushort4* o = (ushort4*)&outp[cbase + oct*128];
          o[0] = make_ushort4(v[0],v[1],v[2],v[3]);
          o[1] = make_ushort4(v[4],v[5],v[6],v[7]);
        }
      }
    }
    __syncthreads();
  }
}

// ---- row softmax: reg-held row, 2 barriers, f32x4 NT out + packed A frags ----
__global__ __launch_bounds__(256) void k_softmax(float* __restrict__ S,
    unsigned short* __restrict__ Apk) {
  __shared__ float w[N_];        // e-values (for the pack)
  __shared__ float redm[4], reds[4];
  int row = blockIdx.x, tid = threadIdx.x;
  float* sr = S + (size_t)row * N_;
  f32x4 v0 = ((const f32x4*)sr)[tid];
  f32x4 v1 = ((const f32x4*)sr)[tid + 256];
  float vmax = fmaxf(fmaxf(fmaxf(v0.x, v0.y), fmaxf(v0.z, v0.w)),
                     fmaxf(fmaxf(v1.x, v1.y), fmaxf(v1.z, v1.w)));
  #pragma unroll
  for (int off = 32; off; off >>= 1) vmax = fmaxf(vmax, __shfl_down(vmax, off, 64));
  if ((tid & 63) == 0) redm[tid >> 6] = vmax;
  __syncthreads();
  vmax = fmaxf(fmaxf(redm[0], redm[1]), fmaxf(redm[2], redm[3]));
  f32x4 e0, e1;
  e0.x = __expf(v0.x - vmax); e0.y = __expf(v0.y - vmax);
  e0.z = __expf(v0.z - vmax); e0.w = __expf(v0.w - vmax);
  e1.x = __expf(v1.x - vmax); e1.y = __expf(v1.y - vmax);
  e1.z = __expf(v1.z - vmax); e1.w = __expf(v1.w - vmax);
  ((f32x4*)w)[tid] = e0;
  ((f32x4*)w)[tid + 256] = e1;
  float vsum = (e0.x + e0.y + e0.z + e0.w) + (e1.x + e1.y + e1.z + e1.w);
  #pragma unroll
  for (int off = 32; off; off >>= 1) vsum += __shfl_down(vsum, off, 64);
  if ((tid & 63) == 0) reds[tid >> 6] = vsum;
  __syncthreads();               // orders reds AND w(e) writes
  float inv = 1.f / ((reds[0] + reds[1]) + (reds[2] + reds[3]));
  f32x4 o0 = e0 * inv, o1 = e1 * inv;
  __builtin_nontemporal_store(o0, &((f32x4*)sr)[tid]);
  __builtin_nontemporal_store(o1, &((f32x4*)sr)[tid + 256]);
  int kt = tid >> 2, j = tid & 3;
  int m0 = kt*32 + j*8;
  int fb = (row >> 4) & 7, rl = row & 15;
  unsigned short v[8];
  #pragma unroll
  for (int e = 0; e < 8; ++e) v[e] = f2bf(w[m0 + e] * inv);
  size_t off_ = ((size_t)((row >> 7)*64 + kt))*4096 + fb*512 + rl*8 + j*128;
  ushort4* o = (ushort4*)&Apk[off_];
  o[0] = make_ushort4(v[0],v[1],v[2],v[3]);
  o[1] = make_ushort4(v[4],v[5],v[6],v[7]);
}

// ---- LayerNorm on H + fused Hp fragment pack ----
__global__ __launch_bounds__(320) void k_ln_pack(const float* __restrict__ H,
    const float* __restrict__ gamma, const float* __restrict__ beta,
    unsigned short* __restrict__ Hp) {
  __shared__ float red[5];
  __shared__ float hs[320];
  int row = blockIdx.x, tid = threadIdx.x;
  float h = (tid < D_) ? H[(size_t)row*D_ + tid] : 0.f;
  float s = h;
  #pragma unroll
  for (int off = 32; off; off >>= 1) s += __shfl_down(s, off, 64);
  if ((tid & 63) == 0) red[tid >> 6] = s;
  __syncthreads();
  float mu = (red[0]+red[1]+red[2]+red[3]+red[4]) * (1.f/(float)D_);
  float dv = (tid < D_) ? (h - mu) : 0.f;
  float s2 = dv * dv;
  #pragma unroll
  for (int off = 32; off; off >>= 1) s2 += __shfl_down(s2, off, 64);
  __syncthreads();
  if ((tid & 63) == 0) red[tid >> 6] = s2;
  __syncthreads();
  float var = (red[0]+red[1]+red[2]+red[3]+red[4]) * (1.f/(float)D_);
  float rstd = rsqrtf(var + 1e-5f);
  hs[tid] = (tid < D_) ? (dv * rstd * gamma[tid] + beta[tid]) : 0.f;
  __syncthreads();
  if (tid < 40) {
    int kt = tid >> 2, j = tid & 3;
    int tile = row >> 7, fb = (row >> 4) & 7, rl = row & 15;
    unsigned short v[8];
    #pragma unroll
    for (int e = 0; e < 8; ++e) v[e] = f2bf(hs[kt*32 + j*8 + e]);
    size_t off_ = ((size_t)(tile*10 + kt))*4096 + fb*512 + rl*8 + j*128;
    ushort4* o = (ushort4*)&Hp[off_];
    o[0] = make_ushort4(v[0],v[1],v[2],v[3]);
    o[1] = make_ushort4(v[4],v[5],v[6],v[7]);
  }
}

extern "C" void kernel_launch(void* const* d_in, const int* in_sizes, int n_in,
                              void* d_out, int out_size, void* d_ws, size_t ws_size,
                              hipStream_t stream) {
  const int*   M_s   = (const int*)d_in[0];
  const float* E_v   = (const float*)d_in[1];
  const float* E_y   = (const float*)d_in[2];
  const float* W_A   = (const float*)d_in[3];
  const float* W_O   = (const float*)d_in[4];
  const float* gamma = (const float*)d_in[5];
  const float* beta  = (const float*)d_in[6];

  float* Yl = (float*)d_out;                       // [8192, 20000]
  float* A  = Yl + (size_t)ROWS * Y_;              // [8192, 2048] (scores -> softmax in place)

  float* X  = (float*)d_ws;                        // [8192,300]
  float* QW = X  + (size_t)ROWS * D_;              // region free (packed path)
  float* H  = QW + (size_t)ROWS * D_;              // [8192,300]
  unsigned short* Ep = (unsigned short*)(H + (size_t)ROWS * D_); // packed E_y (d_ws)
  // Hpk overlays X in d_ws (X dead after residual GEMM); must NOT live in the
  // Yl region the logits GEMM writes (round-8 NaN lesson).
  unsigned short* Hpk = (unsigned short*)X;

  // packed temporaries in the dead tail of the Yl region — all consumed before
  // the final logits GEMM launches (stream-ordered).
  unsigned short* scr = (unsigned short*)(Yl + 100000000ull);
  unsigned short* Xp  = scr;                       // 2,621,440 ush
  unsigned short* QWp = Xp  + 2621440;             // 2,621,440
  unsigned short* Wap = QWp + 2621440;             //   122,880
  unsigned short* Wop = Wap + 122880;              //   122,880
  unsigned short* XTp = Wop + 122880;              // 3,145,728
  unsigned short* Cp  = XTp + 3145728;             // 2,621,440
  unsigned short* Apk = Cp  + 2621440;             // 16,777,216

  k_gather_pack<<<ROWS, 256, 0, stream>>>(M_s, E_v, X, Xp);
  k_packT <<<dim3(3*10,1), 256, 0, stream>>>(W_A, Wap, D_, D_, 10, 0, 0);
  // QW = X @ W_A -> packed QWp (epilogue fusion)
  k_gemm10<0,false,true,false><<<dim3(3,64,1), 256, 0, stream>>>(
      Xp, Wap, nullptr, QWp, nullptr, nullptr, 10, 64, 3, D_);
  // S = QW @ X^T - dist, masked  (256x128 tile, 8 waves, LDS epilogue)
  k_gemm256<1,false,false><<<dim3(16,8,4), 512, 0, stream>>>(
      QWp, Xp, A, M_s, 8, 16, N_);
  k_softmax<<<ROWS, 256, 0, stream>>>(A, Apk);
  k_packT <<<dim3(3*64,4), 256, 0, stream>>>(X, XTp, N_, D_, 64, (size_t)N_*D_, 192);
  // C = A @ X -> packed Cp (KT=64 dbuf)
  k_gemm64<<<dim3(3,16,4), 256, 0, stream>>>(Apk, XTp, Cp, 64, 10, 16, 3);
  k_packT <<<dim3(3*10,1), 256, 0, stream>>>(W_O, Wop, D_, D_, 10, 0, 0);
  // H = C @ W_O + X
  k_gemm10<2,false,false,false><<<dim3(3,64,1), 256, 0, stream>>>(
      Cp, Wop, H, nullptr, X, nullptr, 0, 64, 3, D_);
  k_ln_pack<<<ROWS, 320, 0, stream>>>(H, gamma, beta, Hpk);
  k_pack  <<<157*10, 256, 0, stream>>>(E_y, Ep, Y_, D_, 10);
  // Yl = Hn @ E_y^T  (256x128 tile, 8 waves, XCD swizzle, LDS epi + NT f32x4)
  k_gemm256<0,true,true><<<dim3(157*32,1,1), 512, 0, stream>>>(
      Hpk, Ep, Yl, nullptr, 32, 157, Y_);
}

// Round 19
// 362.679 us; speedup vs baseline: 1.1760x; 1.0303x over previous
//
#include <hip/hip_runtime.h>
#include <hip/hip_bf16.h>

#define B_ 4
#define N_ 2048
#define D_ 300
#define Y_ 20000
#define ROWS (B_*N_)   // 8192

typedef __attribute__((ext_vector_type(8))) short bf16x8;
typedef __attribute__((ext_vector_type(4))) float f32x4;

__device__ __forceinline__ unsigned short f2bf(float f) {  // RNE f32->bf16
  unsigned u = __float_as_uint(f);
  unsigned r = (u + 0x7FFFu + ((u >> 16) & 1u)) >> 16;
  return (unsigned short)r;
}

__device__ __forceinline__ void gl_lds16(const unsigned short* g, unsigned short* l) {
  __builtin_amdgcn_global_load_lds(
      (const __attribute__((address_space(1))) void*)g,
      (__attribute__((address_space(3))) void*)l, 16, 0, 0);
}

// ---- X = E_v[M_s] (f32) + fused Xp pack + folded E_y pack (blocks<1570) ----
__global__ __launch_bounds__(256) void k_gather_pack(const int* __restrict__ M_s,
    const float* __restrict__ E_v, float* __restrict__ X,
    unsigned short* __restrict__ Xp, const float* __restrict__ Ey,
    unsigned short* __restrict__ Ep) {
  __shared__ float xs[320];
  int row = blockIdx.x, tid = threadIdx.x;
  int tok = M_s[row];
  const float* src = E_v + (size_t)tok * D_;
  for (int d = tid; d < 320; d += 256) xs[d] = (d < D_) ? src[d] : 0.f;
  __syncthreads();
  float* dst = X + (size_t)row * D_;
  for (int d = tid; d < D_; d += 256) dst[d] = xs[d];
  if (tid < 40) {
    int kt = tid >> 2, j = tid & 3;
    int tile = row >> 7, fb = (row >> 4) & 7, rl = row & 15;
    unsigned short v[8];
    #pragma unroll
    for (int e = 0; e < 8; ++e) v[e] = f2bf(xs[kt*32 + j*8 + e]);
    size_t off_ = ((size_t)(tile*10 + kt))*4096 + fb*512 + rl*8 + j*128;
    ushort4* o = (ushort4*)&Xp[off_];
    o[0] = make_ushort4(v[0],v[1],v[2],v[3]);
    o[1] = make_ushort4(v[4],v[5],v[6],v[7]);
  }
  // folded E_y fragment pack: one chunk per block for blocks 0..1569
  if (row < 157*10) {
    int tile = row / 10, kt = row - tile*10;
    size_t obase = (size_t)row * 4096;
    #pragma unroll
    for (int p = 0; p < 2; ++p) {
      int idx = p*256 + tid;
      int fb = idx >> 6, l = idx & 63;
      int rr = tile*128 + fb*16 + (l & 15);
      int gk = kt*32 + (l >> 4)*8;
      unsigned short v[8];
      #pragma unroll
      for (int e = 0; e < 8; ++e) {
        int k = gk + e;
        float f = (rr < Y_ && k < D_) ? Ey[(size_t)rr*D_ + k] : 0.f;
        v[e] = f2bf(f);
      }
      ushort4* o = (ushort4*)&Ep[obase + (size_t)idx*8];
      o[0] = make_ushort4(v[0],v[1],v[2],v[3]);
      o[1] = make_ushort4(v[4],v[5],v[6],v[7]);
    }
  }
}

// ---- merged weight transposing pack: y=0 -> (s0,d0), y=1 -> (s1,d1) ----
__global__ __launch_bounds__(256) void k_packTW(const float* __restrict__ s0,
    unsigned short* __restrict__ d0, const float* __restrict__ s1,
    unsigned short* __restrict__ d1) {
  __shared__ float ls[32*133];
  int chunk = blockIdx.x, tid = threadIdx.x;
  const float* s = blockIdx.y ? s1 : s0;
  unsigned short* d = (blockIdx.y ? d1 : d0) + (size_t)chunk * 4096;
  int tile = chunk / 10, kt = chunk - tile*10;
  int c0 = tile*128, k0 = kt*32;
  for (int i = tid; i < 4096; i += 256) {
    int r = i >> 7, c = i & 127;
    int sr = k0 + r, sc = c0 + c;
    ls[r*133 + c] = (sr < D_ && sc < D_) ? s[(size_t)sr*D_ + sc] : 0.f;
  }
  __syncthreads();
  #pragma unroll
  for (int p = 0; p < 2; ++p) {
    int idx = p*256 + tid;
    int fb = idx >> 6, l = idx & 63;
    int r = fb*16 + (l & 15);
    int kl = (l >> 4)*8;
    unsigned short v[8];
    #pragma unroll
    for (int e = 0; e < 8; ++e) v[e] = f2bf(ls[(kl + e)*133 + r]);
    ushort4* o = (ushort4*)&d[(size_t)idx*8];
    o[0] = make_ushort4(v[0],v[1],v[2],v[3]);
    o[1] = make_ushort4(v[4],v[5],v[6],v[7]);
  }
}

// ---- transposing pack via LDS (coalesced source reads) ----
__global__ __launch_bounds__(256) void k_packT(const float* __restrict__ src,
    unsigned short* __restrict__ dst, int src_rows, int src_cols, int KT,
    size_t src_bstride, size_t dst_bchunks) {
  __shared__ float ls[32*133];
  int chunk = blockIdx.x, b = blockIdx.y, tid = threadIdx.x;
  const float* s = src + (size_t)b * src_bstride;
  unsigned short* d = dst + ((size_t)b * dst_bchunks + chunk) * 4096;
  int tile = chunk / KT, kt = chunk - tile*KT;
  int c0 = tile*128, k0 = kt*32;
  for (int i = tid; i < 4096; i += 256) {
    int r = i >> 7, c = i & 127;
    int sr = k0 + r, sc = c0 + c;
    ls[r*133 + c] = (sr < src_rows && sc < src_cols) ? s[(size_t)sr*src_cols + sc] : 0.f;
  }
  __syncthreads();
  #pragma unroll
  for (int p = 0; p < 2; ++p) {
    int idx = p*256 + tid;
    int fb = idx >> 6, l = idx & 63;
    int r = fb*16 + (l & 15);
    int kl = (l >> 4)*8;
    unsigned short v[8];
    #pragma unroll
    for (int e = 0; e < 8; ++e) v[e] = f2bf(ls[(kl + e)*133 + r]);
    ushort4* o = (ushort4*)&d[(size_t)idx*8];
    o[0] = make_ushort4(v[0],v[1],v[2],v[3]);
    o[1] = make_ushort4(v[4],v[5],v[6],v[7]);
  }
}

// ========== 256x128-tile KT=10 GEMM: 8 waves, stage-all-B, barrier-free =====
// LDS epilogue with PAIR-fill: 2 quarters (128 rows) per barrier round -> 4
// epi barriers instead of 8, 4-of-8 waves filling. NT only via coalesced f32x4
// (round-16 lesson: scalar NT fragments bypass L2 write-combining, -51us).
template<int EPI, bool NT, bool SWZ>
__global__ __launch_bounds__(512, 4) void k_gemm256(
    const unsigned short* __restrict__ Ap, const unsigned short* __restrict__ Bp,
    float* __restrict__ out, const int* __restrict__ Ms,
    int MTB, int NTB, int ncols)
{
  __shared__ __align__(16) union {
    unsigned short bstage[10][4096];    // 80 KB (read-only after barrier)
    float epi[128*132];                 // 67.6 KB epilogue pair-tile
  } sm;
  int nt, mt, z;
  if (SWZ) {
    int wg = blockIdx.x;
    int cpx = (MTB*NTB) >> 3;           // caller guarantees grid%8==0
    int swz = (wg & 7)*cpx + (wg >> 3);
    mt = swz % MTB; nt = swz / MTB; z = 0;
  } else { nt = blockIdx.x; mt = blockIdx.y; z = blockIdx.z; }
  const int tid = threadIdx.x;
  const int wave = tid >> 6, lane = tid & 63;
  const int wm = wave >> 1, wn = wave & 1;          // wm 0..3, wn 0..1
  const int mtile2 = (z*MTB + mt)*2 + (wm >> 1);    // which 128-row A tile
  const unsigned short* Ab = Ap + (size_t)mtile2 * 10 * 4096;
  const unsigned short* Bb = Bp + (size_t)(z*NTB + nt) * 10 * 4096;

  #pragma unroll
  for (int kt = 0; kt < 10; ++kt)
    gl_lds16(Bb + kt*4096 + wave*512 + lane*8, &sm.bstage[kt][wave*512]);

  const unsigned short* ga = Ab + ((wm & 1)*4)*512 + lane*8;
  __syncthreads();   // vmcnt(0) drain == all B staged

  f32x4 acc[4][4] = {};
  #pragma unroll
  for (int kt = 0; kt < 10; ++kt) {
    bf16x8 a4[4], b4[4];
    #pragma unroll
    for (int i = 0; i < 4; ++i)
      a4[i] = *(const bf16x8*)(ga + kt*4096 + i*512);
    #pragma unroll
    for (int i = 0; i < 4; ++i)
      b4[i] = *(const bf16x8*)&sm.bstage[kt][(wn*4 + i)*512 + lane*8];
    #pragma unroll
    for (int mi = 0; mi < 4; ++mi)
      #pragma unroll
      for (int ni = 0; ni < 4; ++ni)
        acc[mi][ni] = __builtin_amdgcn_mfma_f32_16x16x32_bf16(
            a4[mi], b4[ni], acc[mi][ni], 0, 0, 0);
  }
  __syncthreads();   // done reading bstage before epi overwrite

  // ---- epilogue: 2 pair-rounds of 128 rows via LDS ----
  const int lr0 = (lane >> 4) << 2;
  const int lc0 = wn*64 + (lane & 15);
  const size_t growbase = ((size_t)(z*MTB + mt)) << 8;
  #pragma unroll
  for (int hp = 0; hp < 2; ++hp) {
    if ((wm >> 1) == hp) {
      int tok[4];
      if (EPI == 1) {
        #pragma unroll
        for (int ni = 0; ni < 4; ++ni)
          tok[ni] = Ms[z*N_ + (nt<<7) + lc0 + ni*16];
      }
      const int rbase = (wm & 1)*64;
      #pragma unroll
      for (int mi = 0; mi < 4; ++mi) {
        #pragma unroll
        for (int ni = 0; ni < 4; ++ni) {
          int col = lc0 + ni*16;
          #pragma unroll
          for (int r = 0; r < 4; ++r) {
            int row = rbase + lr0 + mi*16 + r;      // 0..127 in pair
            float v = acc[mi][ni][r];
            if (EPI == 1) {
              int rb = (mt<<8) + hp*128 + row;      // row within batch
              int gc = (nt<<7) + col;
              int dd = rb - gc; if (dd < 0) dd = -dd; if (dd > 10) dd = 10;
              v -= (float)dd;
              if (tok[ni] == 0) v = -3.0e38f;
            }
            sm.epi[row*132 + col] = v;
          }
        }
      }
    }
    __syncthreads();
    {
      const int r0 = tid >> 5;            // 0..15
      const int c4 = (tid & 31) << 2;     // 0..124
      const int gc = (nt << 7) + c4;
      #pragma unroll
      for (int rr = r0; rr < 128; rr += 16) {
        size_t grow = growbase + hp*128 + rr;
        if (gc + 3 < ncols) {
          f32x4 v = *(const f32x4*)&sm.epi[rr*132 + c4];
          if (NT) __builtin_nontemporal_store(v, (f32x4*)&out[grow*(size_t)ncols + gc]);
          else    *(f32x4*)&out[grow*(size_t)ncols + gc] = v;
        } else {
          #pragma unroll
          for (int e = 0; e < 4; ++e) {
            int c = gc + e;
            if (c < ncols) {
              float v = sm.epi[rr*132 + c4 + e];
              if (NT) __builtin_nontemporal_store(v, &out[grow*(size_t)ncols + c]);
              else    out[grow*(size_t)ncols + c] = v;
            }
          }
        }
      }
    }
    __syncthreads();
  }
}

// ====== KT=10 GEMM (128x128): stage-all-B, barrier-free, 1-round epilogue ===
template<int EPI, bool NT, bool PACKOUT, bool SWZ>
__global__ __launch_bounds__(256) void k_gemm10(
    const unsigned short* __restrict__ Ap, const unsigned short* __restrict__ Bp,
    float* __restrict__ out, unsigned short* __restrict__ outp,
    const float* __restrict__ resid, const int* __restrict__ Ms,
    int KTd, int MTB, int NTB, int ncols)
{
  __shared__ __align__(16) union {
    unsigned short bstage[10][4096];    // 80 KB
    float epi[128*132];                 // 67.6 KB
  } sm;
  int nt, mt, z;
  if (SWZ) {
    int nwg = MTB * NTB;
    int wg = blockIdx.x;
    int cpx = nwg >> 3;
    int swz = (wg & 7) * cpx + (wg >> 3);
    mt = swz % MTB; nt = swz / MTB; z = 0;
  } else {
    nt = blockIdx.x; mt = blockIdx.y; z = blockIdx.z;
  }
  const int tid = threadIdx.x;
  const int wave = tid >> 6, lane = tid & 63;
  const int wm = wave >> 1, wn = wave & 1;
  const unsigned short* Ab = Ap + (size_t)(z*MTB + mt) * 10 * 4096;
  const unsigned short* Bb = Bp + (size_t)(z*NTB + nt) * 10 * 4096;

  #pragma unroll
  for (int kt = 0; kt < 10; ++kt) {
    const unsigned short* gb = Bb + kt*4096 + wave*1024 + lane*8;
    unsigned short* lb = &sm.bstage[kt][wave*1024];
    gl_lds16(gb,       lb);
    gl_lds16(gb + 512, lb + 512);
  }

  const unsigned short* ga = Ab + (wm*4)*512 + lane*8;
  bf16x8 aA[4], aB[4];
  #pragma unroll
  for (int i = 0; i < 4; ++i) aA[i] = *(const bf16x8*)(ga + 0*4096 + i*512);
  #pragma unroll
  for (int i = 0; i < 4; ++i) aB[i] = *(const bf16x8*)(ga + 1*4096 + i*512);

  __syncthreads();

  f32x4 acc[4][4] = {};
  auto mfma_step = [&](int kt, const bf16x8* a) {
    bf16x8 bfr[4];
    #pragma unroll
    for (int i = 0; i < 4; ++i)
      bfr[i] = *(const bf16x8*)&sm.bstage[kt][(wn*4 + i)*512 + lane*8];
    #pragma unroll
    for (int mi = 0; mi < 4; ++mi)
      #pragma unroll
      for (int ni = 0; ni < 4; ++ni)
        acc[mi][ni] = __builtin_amdgcn_mfma_f32_16x16x32_bf16(
            a[mi], bfr[ni], acc[mi][ni], 0, 0, 0);
  };
  auto loadA = [&](int kt, bf16x8* d) {
    #pragma unroll
    for (int i = 0; i < 4; ++i) d[i] = *(const bf16x8*)(ga + kt*4096 + i*512);
  };

  #pragma unroll
  for (int kt = 0; kt < 10; kt += 2) {
    mfma_step(kt, aA);
    if (kt + 2 < 10) loadA(kt + 2, aA);
    mfma_step(kt + 1, aB);
    if (kt + 3 < 10) loadA(kt + 3, aB);
  }

  __syncthreads();

  // ---- single-round 128-row epilogue (all 4 waves fill) ----
  const int lr0 = (lane >> 4) << 2;
  const int lc0 = wn*64 + (lane & 15);
  const size_t growbase = ((size_t)(z*MTB + mt)) << 7;
  {
    int tok[4];
    if (EPI == 1) {
      #pragma unroll
      for (int ni = 0; ni < 4; ++ni)
        tok[ni] = Ms[z*N_ + (nt<<7) + lc0 + ni*16];
    }
    const int rbase = wm*64;
    #pragma unroll
    for (int mi = 0; mi < 4; ++mi) {
      #pragma unroll
      for (int ni = 0; ni < 4; ++ni) {
        int col = lc0 + ni*16;
        #pragma unroll
        for (int r = 0; r < 4; ++r) {
          int row = rbase + lr0 + mi*16 + r;        // 0..127
          float v = acc[mi][ni][r];
          if (EPI == 1) {
            int rb = (mt<<7) + row;
            int gc = (nt<<7) + col;
            int dd = rb - gc; if (dd < 0) dd = -dd; if (dd > 10) dd = 10;
            v -= (float)dd;
            if (tok[ni] == 0) v = -3.0e38f;
          }
          sm.epi[row*132 + col] = v;
        }
      }
    }
  }
  __syncthreads();
  if (PACKOUT) {
    #pragma unroll
    for (int p = 0; p < 2; ++p) {
      int row = p*64 + (tid >> 2), pktq = tid & 3;
      int ktd = nt*4 + pktq;
      if (ktd < KTd) {
        int fb = row >> 4, rl = row & 15;
        size_t cbase = ((size_t)((z*MTB + mt)*KTd + ktd))*4096 + fb*512 + rl*8;
        #pragma unroll
        for (int oct = 0; oct < 4; ++oct) {
          unsigned short v[8];
          #pragma unroll
          for (int e = 0; e < 8; ++e)
            v[e] = f2bf(sm.epi[row*132 + pktq*32 + oct*8 + e]);
          ushort4* o = (ushort4*)&outp[cbase + oct*128];
          o[0] = make_ushort4(v[0],v[1],v[2],v[3]);
          o[1] = make_ushort4(v[4],v[5],v[6],v[7]);
        }
      }
    }
  } else {
    const int r0 = tid >> 5;
    const int c4 = (tid & 31) << 2;
    const int gc = (nt << 7) + c4;
    #pragma unroll
    for (int rr = r0; rr < 128; rr += 8) {
      size_t grow = growbase + rr;
      if (gc + 3 < ncols) {
        f32x4 v = *(const f32x4*)&sm.epi[rr*132 + c4];
        if (EPI == 2) v += *(const f32x4*)&resid[grow*(size_t)ncols + gc];
        if (NT) __builtin_nontemporal_store(v, (f32x4*)&out[grow*(size_t)ncols + gc]);
        else    *(f32x4*)&out[grow*(size_t)ncols + gc] = v;
      } else {
        #pragma unroll
        for (int e = 0; e < 4; ++e) {
          int c = gc + e;
          if (c < ncols) {
            float v = sm.epi[rr*132 + c4 + e];
            if (EPI == 2) v += resid[grow*(size_t)ncols + c];
            if (NT) __builtin_nontemporal_store(v, &out[grow*(size_t)ncols + c]);
            else    out[grow*(size_t)ncols + c] = v;
          }
        }
      }
    }
  }
}

// ===== KT=64 GEMM (C = A@X): double-buffered + PACKOUT, 1-round epilogue ====
__global__ __launch_bounds__(256) void k_gemm64(
    const unsigned short* __restrict__ Ap, const unsigned short* __restrict__ Bp,
    unsigned short* __restrict__ outp, int KT, int KTd, int MTB, int NTB)
{
  __shared__ __align__(16) union {
    unsigned short stage[2][2][4096];   // 32 KB dbuf
    float epi[128*132];                 // 67.6 KB
  } sm;
  const int nt = blockIdx.x, mt = blockIdx.y, z = blockIdx.z;
  const int tid = threadIdx.x;
  const int wave = tid >> 6, lane = tid & 63;
  const int wm = wave >> 1, wn = wave & 1;
  const unsigned short* Ab = Ap + (size_t)(z*MTB + mt) * KT * 4096;
  const unsigned short* Bb = Bp + (size_t)(z*NTB + nt) * KT * 4096;
  f32x4 acc[4][4] = {};

  auto stage = [&](int s, int kt) {
    const unsigned short* ga = Ab + kt*4096 + wave*1024 + lane*8;
    const unsigned short* gb = Bb + kt*4096 + wave*1024 + lane*8;
    unsigned short* la = &sm.stage[s][0][wave*1024];
    unsigned short* lb = &sm.stage[s][1][wave*1024];
    gl_lds16(ga,       la);
    gl_lds16(ga + 512, la + 512);
    gl_lds16(gb,       lb);
    gl_lds16(gb + 512, lb + 512);
  };

  stage(0, 0);
  __syncthreads();
  for (int kt = 0; kt < KT; ++kt) {
    int cur = kt & 1;
    if (kt + 1 < KT) stage(cur ^ 1, kt + 1);
    bf16x8 af[4], bfr[4];
    #pragma unroll
    for (int i = 0; i < 4; ++i)
      af[i] = *(const bf16x8*)&sm.stage[cur][0][(wm*4 + i)*512 + lane*8];
    #pragma unroll
    for (int i = 0; i < 4; ++i)
      bfr[i] = *(const bf16x8*)&sm.stage[cur][1][(wn*4 + i)*512 + lane*8];
    #pragma unroll
    for (int mi = 0; mi < 4; ++mi)
      #pragma unroll
      for (int ni = 0; ni < 4; ++ni)
        acc[mi][ni] = __builtin_amdgcn_mfma_f32_16x16x32_bf16(
            af[mi], bfr[ni], acc[mi][ni], 0, 0, 0);
    __syncthreads();
  }

  const int lr0 = (lane >> 4) << 2;
  const int lc0 = wn*64 + (lane & 15);
  {
    const int rbase = wm*64;
    #pragma unroll
    for (int mi = 0; mi < 4; ++mi)
      #pragma unroll
      for (int ni = 0; ni < 4; ++ni) {
        int col = lc0 + ni*16;
        #pragma unroll
        for (int r = 0; r < 4; ++r)
          sm.epi[(rbase + lr0 + mi*16 + r)*132 + col] = acc[mi][ni][r];
      }
  }
  __syncthreads();
  #pragma unroll
  for (int p = 0; p < 2; ++p) {
    int row = p*64 + (tid >> 2), pktq = tid & 3;
    int ktd = nt*4 + pktq;
    if (ktd < KTd) {
      int fb = row >> 4, rl = row & 15;
      size_t cbase = ((size_t)((z*MTB + mt)*KTd + ktd))*4096 + fb*512 + rl*8;
      #pragma unroll
      for (int oct = 0; oct < 4; ++oct) {
        unsigned short v[8];
        #pragma unroll
        for (int e = 0; e < 8; ++e)
          v[e] = f2bf(sm.epi[row*132 + pktq*32 + oct*8 + e]);
        ushort4* o = (ushort4*)&outp[cbase + oct*128];
        o[0] = make_ushort4(v[0],v[1],v[2],v[3]);
        o[1] = make_ushort4(v[4],v[5],v[6],v[7]);
      }
    }
  }
}

// ---- row softmax: reg-held row, 2 barriers, f32x4 NT out + packed A frags ----
__global__ __launch_bounds__(256) void k_softmax(float* __restrict__ S,
    unsigned short* __restrict__ Apk) {
  __shared__ float w[N_];        // e-values (for the pack)
  __shared__ float redm[4], reds[4];
  int row = blockIdx.x, tid = threadIdx.x;
  float* sr = S + (size_t)row * N_;
  f32x4 v0 = ((const f32x4*)sr)[tid];
  f32x4 v1 = ((const f32x4*)sr)[tid + 256];
  float vmax = fmaxf(fmaxf(fmaxf(v0.x, v0.y), fmaxf(v0.z, v0.w)),
                     fmaxf(fmaxf(v1.x, v1.y), fmaxf(v1.z, v1.w)));
  #pragma unroll
  for (int off = 32; off; off >>= 1) vmax = fmaxf(vmax, __shfl_down(vmax, off, 64));
  if ((tid & 63) == 0) redm[tid >> 6] = vmax;
  __syncthreads();
  vmax = fmaxf(fmaxf(redm[0], redm[1]), fmaxf(redm[2], redm[3]));
  f32x4 e0, e1;
  e0.x = __expf(v0.x - vmax); e0.y = __expf(v0.y - vmax);
  e0.z = __expf(v0.z - vmax); e0.w = __expf(v0.w - vmax);
  e1.x = __expf(v1.x - vmax); e1.y = __expf(v1.y - vmax);
  e1.z = __expf(v1.z - vmax); e1.w = __expf(v1.w - vmax);
  ((f32x4*)w)[tid] = e0;
  ((f32x4*)w)[tid + 256] = e1;
  float vsum = (e0.x + e0.y + e0.z + e0.w) + (e1.x + e1.y + e1.z + e1.w);
  #pragma unroll
  for (int off = 32; off; off >>= 1) vsum += __shfl_down(vsum, off, 64);
  if ((tid & 63) == 0) reds[tid >> 6] = vsum;
  __syncthreads();               // orders reds AND w(e) writes
  float inv = 1.f / ((reds[0] + reds[1]) + (reds[2] + reds[3]));
  f32x4 o0 = e0 * inv, o1 = e1 * inv;
  __builtin_nontemporal_store(o0, &((f32x4*)sr)[tid]);
  __builtin_nontemporal_store(o1, &((f32x4*)sr)[tid + 256]);
  int kt = tid >> 2, j = tid & 3;
  int m0 = kt*32 + j*8;
  int fb = (row >> 4) & 7, rl = row & 15;
  unsigned short v[8];
  #pragma unroll
  for (int e = 0; e < 8; ++e) v[e] = f2bf(w[m0 + e] * inv);
  size_t off_ = ((size_t)((row >> 7)*64 + kt))*4096 + fb*512 + rl*8 + j*128;
  ushort4* o = (ushort4*)&Apk[off_];
  o[0] = make_ushort4(v[0],v[1],v[2],v[3]);
  o[1] = make_ushort4(v[4],v[5],v[6],v[7]);
}

// ---- LayerNorm on H + fused Hp fragment pack ----
__global__ __launch_bounds__(320) void k_ln_pack(const float* __restrict__ H,
    const float* __restrict__ gamma, const float* __restrict__ beta,
    unsigned short* __restrict__ Hp) {
  __shared__ float red[5];
  __shared__ float hs[320];
  int row = blockIdx.x, tid = threadIdx.x;
  float h = (tid < D_) ? H[(size_t)row*D_ + tid] : 0.f;
  float s = h;
  #pragma unroll
  for (int off = 32; off; off >>= 1) s += __shfl_down(s, off, 64);
  if ((tid & 63) == 0) red[tid >> 6] = s;
  __syncthreads();
  float mu = (red[0]+red[1]+red[2]+red[3]+red[4]) * (1.f/(float)D_);
  float dv = (tid < D_) ? (h - mu) : 0.f;
  float s2 = dv * dv;
  #pragma unroll
  for (int off = 32; off; off >>= 1) s2 += __shfl_down(s2, off, 64);
  __syncthreads();
  if ((tid & 63) == 0) red[tid >> 6] = s2;
  __syncthreads();
  float var = (red[0]+red[1]+red[2]+red[3]+red[4]) * (1.f/(float)D_);
  float rstd = rsqrtf(var + 1e-5f);
  hs[tid] = (tid < D_) ? (dv * rstd * gamma[tid] + beta[tid]) : 0.f;
  __syncthreads();
  if (tid < 40) {
    int kt = tid >> 2, j = tid & 3;
    int tile = row >> 7, fb = (row >> 4) & 7, rl = row & 15;
    unsigned short v[8];
    #pragma unroll
    for (int e = 0; e < 8; ++e) v[e] = f2bf(hs[kt*32 + j*8 + e]);
    size_t off_ = ((size_t)(tile*10 + kt))*4096 + fb*512 + rl*8 + j*128;
    ushort4* o = (ushort4*)&Hp[off_];
    o[0] = make_ushort4(v[0],v[1],v[2],v[3]);
    o[1] = make_ushort4(v[4],v[5],v[6],v[7]);
  }
}

extern "C" void kernel_launch(void* const* d_in, const int* in_sizes, int n_in,
                              void* d_out, int out_size, void* d_ws, size_t ws_size,
                              hipStream_t stream) {
  const int*   M_s   = (const int*)d_in[0];
  const float* E_v   = (const float*)d_in[1];
  const float* E_y   = (const float*)d_in[2];
  const float* W_A   = (const float*)d_in[3];
  const float* W_O   = (const float*)d_in[4];
  const float* gamma = (const float*)d_in[5];
  const float* beta  = (const float*)d_in[6];

  float* Yl = (float*)d_out;                       // [8192, 20000]
  float* A  = Yl + (size_t)ROWS * Y_;              // [8192, 2048] (scores -> softmax in place)

  float* X  = (float*)d_ws;                        // [8192,300]
  float* QW = X  + (size_t)ROWS * D_;              // region free (packed path)
  float* H  = QW + (size_t)ROWS * D_;              // [8192,300]
  unsigned short* Ep = (unsigned short*)(H + (size_t)ROWS * D_); // packed E_y (d_ws)
  // Hpk overlays X in d_ws (X dead after residual GEMM); must NOT live in the
  // Yl region the logits GEMM writes (round-8 NaN lesson).
  unsigned short* Hpk = (unsigned short*)X;

  // packed temporaries in the dead tail of the Yl region — all consumed before
  // the final logits GEMM launches (stream-ordered).
  unsigned short* scr = (unsigned short*)(Yl + 100000000ull);
  unsigned short* Xp  = scr;                       // 2,621,440 ush
  unsigned short* QWp = Xp  + 2621440;             // 2,621,440
  unsigned short* Wap = QWp + 2621440;             //   122,880
  unsigned short* Wop = Wap + 122880;              //   122,880
  unsigned short* XTp = Wop + 122880;              // 3,145,728
  unsigned short* Cp  = XTp + 3145728;             // 2,621,440
  unsigned short* Apk = Cp  + 2621440;             // 16,777,216

  k_gather_pack<<<ROWS, 256, 0, stream>>>(M_s, E_v, X, Xp, E_y, Ep);
  k_packTW<<<dim3(30, 2), 256, 0, stream>>>(W_A, Wap, W_O, Wop);
  // QW = X @ W_A -> packed QWp (epilogue fusion)
  k_gemm10<0,false,true,false><<<dim3(3,64,1), 256, 0, stream>>>(
      Xp, Wap, nullptr, QWp, nullptr, nullptr, 10, 64, 3, D_);
  // S = QW @ X^T - dist, masked  (256x128 tile, 8 waves, pair-fill LDS epi)
  k_gemm256<1,false,false><<<dim3(16,8,4), 512, 0, stream>>>(
      QWp, Xp, A, M_s, 8, 16, N_);
  k_softmax<<<ROWS, 256, 0, stream>>>(A, Apk);
  k_packT <<<dim3(3*64,4), 256, 0, stream>>>(X, XTp, N_, D_, 64, (size_t)N_*D_, 192);
  // C = A @ X -> packed Cp (KT=64 dbuf)
  k_gemm64<<<dim3(3,16,4), 256, 0, stream>>>(Apk, XTp, Cp, 64, 10, 16, 3);
  // H = C @ W_O + X
  k_gemm10<2,false,false,false><<<dim3(3,64,1), 256, 0, stream>>>(
      Cp, Wop, H, nullptr, X, nullptr, 0, 64, 3, D_);
  k_ln_pack<<<ROWS, 320, 0, stream>>>(H, gamma, beta, Hpk);
  // Yl = Hn @ E_y^T  (256x128 tile, 8 waves, XCD swizzle, pair-fill epi + NT)
  k_gemm256<0,true,true><<<dim3(157*32,1,1), 512, 0, stream>>>(
      Hpk, Ep, Yl, nullptr, 32, 157, Y_);
}